// Round 6
// baseline (70.185 us; speedup 1.0000x reference)
//
#include <hip/hip_runtime.h>
#include <utility>

#define NQ 14
#define NST (1 << NQ)      // 16384
#define THREADS 1024

// ---------------- compile-time schedule ----------------
struct PassD {
    unsigned short comboS[16];  // pre-swizzled xor offsets (element units)
    unsigned short rows[4];     // R row (base-parity mask) per tile bit
    unsigned short tmask[4];    // C column (tile span mask) per tile bit
    unsigned short crx_widx[3]; // CRX gate weight indices (chain at tile bits g,g+1)
    unsigned short ry_widx[3];  // folded next-block RY weight indices
    unsigned char  ry_tb[3];    // tile bit each folded RY acts on
    unsigned char  ncrx;        // 2 or 3
    unsigned char  nry;         // 0..3
    short          rzidx;       // >=0: fold RZ layer before CRX chain
    unsigned char  measfold;    // 1: fold measurement, skip store
};
struct RZD  { unsigned short rows_ng[10]; unsigned short widx_ng[10]; unsigned short widx_g[4]; };
struct AllD { PassD pass[20]; RZD rz[4]; unsigned short meas_rows_ng[10]; int npass; };

__host__ __device__ constexpr int swz(int i) { return i ^ ((((i >> 1) ^ (i >> 3) ^ (i >> 5))) & 31); }

constexpr void fill_geom(PassD& P, const unsigned short* R, const unsigned short* C, const int* tb)
{
    for (int i = 0; i < 4; ++i) { P.tmask[i] = C[tb[i]]; P.rows[i] = R[tb[i]]; }
    for (int j = 0; j < 16; ++j) {
        unsigned short x = 0;
        for (int i = 0; i < 4; ++i) if ((j >> i) & 1) x = (unsigned short)(x ^ P.tmask[i]);
        P.comboS[j] = (unsigned short)swz(x);
    }
}

constexpr void ring(unsigned short* R, unsigned short* C) {
    for (int q = 0; q < NQ; ++q) {
        int cb = 13 - q, tb = 13 - ((q + 1) % NQ);
        R[tb] = (unsigned short)(R[tb] ^ R[cb]);
        C[cb] = (unsigned short)(C[cb] ^ C[tb]);
    }
}

constexpr AllD build_desc() {
    AllD A{};
    unsigned short R[NQ] = {}, C[NQ] = {};
    for (int k = 0; k < NQ; ++k) { R[k] = (unsigned short)(1u << k); C[k] = (unsigned short)(1u << k); }
    int np = 0;
    const int tiles[5][4] = {{13,12,11,10},{10,9,8,7},{7,6,5,4},{4,3,2,1},{1,0,13,2}};
    const int gfirst[5]   = {0, 3, 6, 9, 12};
    const int ngate[5]    = {3, 3, 3, 3, 2};
    const int rybits[5][3]= {{11,12,0},{10,9,8},{7,6,5},{4,3,2},{13,1,0}};
    const int nryp[5]     = {2, 3, 3, 3, 3};

    for (int blk = 0; blk < 4; ++blk) {
        ring(R, C);   // CNOT ring = pure relabeling
        for (int pi = 0; pi < 5; ++pi) {
            PassD& P = A.pass[np];
            fill_geom(P, R, C, tiles[pi]);
            P.ncrx = (unsigned char)ngate[pi];
            for (int g = 0; g < 3; ++g)
                P.crx_widx[g] = (unsigned short)((g < ngate[pi]) ? blk*42 + 28 + gfirst[pi] + g : 0);
            if (blk < 3) {
                P.nry = (unsigned char)nryp[pi];
                for (int g = 0; g < 3; ++g) {
                    if (g < nryp[pi]) {
                        int k = rybits[pi][g];                       // state bit
                        P.ry_widx[g] = (unsigned short)((blk + 1)*42 + (13 - k));
                        int t = 0;
                        for (int i = 0; i < 4; ++i) if (tiles[pi][i] == k) t = i;
                        P.ry_tb[g] = (unsigned char)t;
                    } else { P.ry_widx[g] = 0; P.ry_tb[g] = 0; }
                }
            } else { P.nry = 0; for (int g = 0; g < 3; ++g) { P.ry_widx[g] = 0; P.ry_tb[g] = 0; } }
            P.rzidx = (short)((pi == 0) ? blk : -1);
            P.measfold = (unsigned char)((blk == 3 && pi == 4) ? 1 : 0);
            if (pi == 0) {
                RZD& Z = A.rz[blk];
                for (int i = 0; i < 4; ++i)
                    Z.widx_g[i] = (unsigned short)(blk*42 + 14 + (13 - tiles[0][i]));
                int t = 0;
                for (int q = 4; q < NQ; ++q, ++t) {
                    Z.rows_ng[t] = R[13 - q];
                    Z.widx_ng[t] = (unsigned short)(blk*42 + 14 + q);
                }
            }
            ++np;
        }
        if (blk == 3)
            for (int t = 0; t < 10; ++t) A.meas_rows_ng[t] = R[13 - (1 + t)];
    }
    A.npass = np;
    return A;
}

constexpr AllD A = build_desc();
static_assert(A.npass == 20, "expected 20 passes");

constexpr int parity14(unsigned v) { v ^= v >> 8; v ^= v >> 4; v ^= v >> 2; v ^= v >> 1; return (int)(v & 1); }

// R/C duality: parity(rows[i] & tmask[j]) == delta_ij  (basis of the M-projection)
constexpr bool check_dual() {
    for (int p = 0; p < 20; ++p)
        for (int i = 0; i < 4; ++i)
            for (int j = 0; j < 4; ++j)
                if (parity14((unsigned)(A.pass[p].rows[i] & A.pass[p].tmask[j])) != (i == j ? 1 : 0))
                    return false;
    return true;
}
static_assert(check_dual(), "R/C duality violated");

// flat gate-weight-index table (slots 0-2 CRX, 3-5 RY)
struct GWT { unsigned short w[20][6]; };
constexpr GWT build_gwt() {
    GWT g{};
    for (int p = 0; p < 20; ++p) {
        for (int s = 0; s < 3; ++s) g.w[p][s]     = A.pass[p].crx_widx[s];
        for (int s = 0; s < 3; ++s) g.w[p][3 + s] = A.pass[p].ry_widx[s];
    }
    return g;
}
constexpr GWT GW = build_gwt();

// ---------------- GF(2) machinery ----------------
constexpr int lead(unsigned short v) { int b = 13; while (b > 0 && !((v >> b) & 1)) --b; return b; }

struct Span {
    unsigned short red[14]; int n;
    constexpr unsigned short reduce(unsigned short v) const {
        for (int i = 0; i < n; ++i) { int lb = lead(red[i]); if ((v >> lb) & 1) v = (unsigned short)(v ^ red[i]); }
        return v;
    }
    constexpr bool add(unsigned short v) {
        unsigned short r = reduce(v);
        if (!r) return false;
        red[n++] = r; return true;
    }
};

// M-projection: zero all 4 tile parities by shifting the representative within
// its tile coset. Linear (simultaneous parities of the ORIGINAL vec), so it
// folds into the XOR-split LUTs. After M, tile index bit t == logical value
// of the qubit at tile bit t, for every thread and element.
constexpr unsigned short proj(unsigned short vec, const PassD& P) {
    unsigned short r = vec;
    for (int t = 0; t < 4; ++t)
        if (parity14((unsigned)(vec & P.rows[t]))) r = (unsigned short)(r ^ P.tmask[t]);
    return r;
}

// entry = (swz(M(vec))<<3) | (nongroup_parity_bits << 22)
// nongroup bits: rz rows_ng OR meas_rows_ng (per pass); group parities are 0 by M.
constexpr unsigned pack_entry(unsigned short vec0, const PassD& P) {
    unsigned short vec = proj(vec0, P);
    unsigned par = 0;
    if (P.rzidx >= 0)
        for (int t = 0; t < 10; ++t) par |= (unsigned)parity14(vec & A.rz[P.rzidx].rows_ng[t]) << t;
    if (P.measfold)
        for (int t = 0; t < 10; ++t) par |= (unsigned)parity14(vec & A.meas_rows_ng[t]) << t;
    return ((unsigned)swz(vec) << 3) | (par << 22);
}

struct LutsT { unsigned v[20][2][32]; int ok; };

constexpr LutsT build_luts() {
    LutsT L{};
    L.ok = 1;
    for (int k = 0; k < 10; ++k) {
        const PassD& P0 = A.pass[2*k];
        const PassD& P1 = A.pass[2*k + 1];
        // W = span(T0 ∪ T1) extended to dim 10
        Span SW{}; unsigned short Wb[10] = {}; int nw = 0;
        for (int i = 0; i < 4; ++i) if (SW.add(P0.tmask[i])) Wb[nw++] = P0.tmask[i];
        for (int i = 0; i < 4; ++i) if (nw < 10 && SW.add(P1.tmask[i])) Wb[nw++] = P1.tmask[i];
        for (int b = 0; b < 14 && nw < 10; ++b) {
            unsigned short e = (unsigned short)(1u << b);
            if (SW.add(e)) Wb[nw++] = e;
        }
        if (nw != 10) L.ok = 0;
        // wave-bit complement g[4] (shared by both passes of the pair)
        Span SG = SW; unsigned short g[4] = {}; int ngv = 0;
        for (int b = 0; b < 14 && ngv < 4; ++b) {
            unsigned short e = (unsigned short)(1u << b);
            if (SG.add(e)) g[ngv++] = e;
        }
        if (ngv != 4) L.ok = 0;
        for (int pp = 0; pp < 2; ++pp) {
            const PassD& P = (pp == 0) ? P0 : P1;
            int pidx = 2*k + pp;
            // lane vectors: completion of T inside W
            unsigned short lane[6] = {}; int nl = 0;
            {
                Span STl{};
                for (int i = 0; i < 4; ++i) STl.add(P.tmask[i]);
                for (int i = 0; i < 10 && nl < 6; ++i)
                    if (STl.add(Wb[i])) lane[nl++] = Wb[i];
            }
            if (nl != 6) L.ok = 0;
            // bijectivity check: T ∪ lane ∪ g spans F_2^14  (M preserves cosets,
            // so enumeration bijectivity is unaffected by proj)
            {
                Span SF{};
                for (int i = 0; i < 4; ++i) SF.add(P.tmask[i]);
                for (int i = 0; i < 6; ++i) if (!SF.add(lane[i])) L.ok = 0;
                for (int i = 0; i < 4; ++i) if (!SF.add(g[i])) L.ok = 0;
                if (SF.n != 14) L.ok = 0;
            }
            // emit LUTs: tid bits 0..4 -> lane[0..4]; bit5 -> lane[5]; bits6..9 -> g[0..3]
            for (int t = 0; t < 32; ++t) {
                unsigned short x = 0;
                for (int i = 0; i < 5; ++i) if ((t >> i) & 1) x = (unsigned short)(x ^ lane[i]);
                L.v[pidx][0][t] = pack_entry(x, P);
                unsigned short y = 0;
                if (t & 1) y = (unsigned short)(y ^ lane[5]);
                for (int i = 0; i < 4; ++i) if ((t >> (i + 1)) & 1) y = (unsigned short)(y ^ g[i]);
                L.v[pidx][1][t] = pack_entry(y, P);
            }
        }
    }
    return L;
}

constexpr LutsT LUTS = build_luts();
static_assert(LUTS.ok == 1, "LUT construction failed (rank check)");

__device__ __constant__ LutsT cLUTS = LUTS;

// ---------------- per-pass device code (fully constant-folded) ----------------
template<int Pi>
__device__ __forceinline__ void run_pass(float2* st, const float (*tabG)[6][2], const float (*tabRZ)[14],
                                         unsigned comb, float* acc)
{
    constexpr PassD Pd = A.pass[Pi];
    char* stb = (char*)st;
    const int base = (int)(comb & 0x1FFF8u);   // pre-swizzled byte offset (M-canonical)
    const unsigned par = comb >> 22;           // non-group parity bits

    float2 v[16];
#pragma unroll
    for (int j = 0; j < 16; ++j)
        v[j] = *(const float2*)(stb + (base ^ (Pd.comboS[j] << 3)));

    // ---- fused RZ layer (first pass of each block; before the CRX chain) ----
    // After M, the group-qubit sign is the tile index bit itself (compile-time).
    if constexpr (Pd.rzidx >= 0) {
        float phi0 = 0.f;
#pragma unroll
        for (int t = 0; t < 10; ++t) {
            float h = tabRZ[Pd.rzidx][t];
            phi0 += ((par >> t) & 1) ? h : -h;
        }
        const float h0 = tabRZ[Pd.rzidx][10], h1 = tabRZ[Pd.rzidx][11];
        const float h2 = tabRZ[Pd.rzidx][12], h3 = tabRZ[Pd.rzidx][13];
#pragma unroll
        for (int j = 0; j < 16; ++j) {
            float phi = ((((phi0 + ((j & 1) ? h0 : -h0)) + ((j & 2) ? h1 : -h1))
                                 + ((j & 4) ? h2 : -h2)) + ((j & 8) ? h3 : -h3));
            float s, c; __sincosf(phi, &s, &c);
            float2 a = v[j];
            v[j] = make_float2(a.x * c - a.y * s, a.y * c + a.x * s);
        }
    }

    // ---- CRX chain: control = tile bit g (logical!), target = tile bit g+1 ----
    // M-canonical: control==1 ⇔ j bit g == 1 — identity pairs skipped entirely.
#pragma unroll
    for (int g = 0; g < Pd.ncrx; ++g) {
        float c = tabG[Pi][g][0], s = tabG[Pi][g][1];
#pragma unroll
        for (int j = 0; j < 16; ++j) if (((j >> g) & 1) && !((j >> (g + 1)) & 1)) {
            int j1 = j | (1 << (g + 1));
            float2 a0 = v[j], a1 = v[j1];
            // RX on target: new0 = c*a0 - i s*a1 ; new1 = c*a1 - i s*a0
            v[j]  = make_float2(c * a0.x + s * a1.y, c * a0.y - s * a1.x);
            v[j1] = make_float2(c * a1.x + s * a0.y, c * a1.y - s * a0.x);
        }
    }

    // ---- folded next-block RY gates (no sign select after M) ----
#pragma unroll
    for (int g = 0; g < Pd.nry; ++g) {
        int t = Pd.ry_tb[g];   // compile-time after unroll
        float c = tabG[Pi][3 + g][0], s = tabG[Pi][3 + g][1];
#pragma unroll
        for (int j = 0; j < 16; ++j) if (!((j >> t) & 1)) {
            int j1 = j | (1 << t);
            float2 a0 = v[j], a1 = v[j1];
            v[j]  = make_float2(c * a0.x - s * a1.x, c * a0.y - s * a1.y);
            v[j1] = make_float2(s * a0.x + c * a1.x, s * a0.y + c * a1.y);
        }
    }

    if constexpr (Pd.measfold != 0) {
        float psum = 0.f, pg0 = 0.f, pg1 = 0.f, pg2 = 0.f, pg3 = 0.f;
#pragma unroll
        for (int j = 0; j < 16; ++j) {
            float pj = v[j].x * v[j].x + v[j].y * v[j].y;
            psum += pj;
            if (j & 1) pg0 += pj;
            if (j & 2) pg1 += pj;
            if (j & 4) pg2 += pj;
            if (j & 8) pg3 += pj;
        }
        // tile state bits {1,0,13,2} = JAX qubits {12,13,0,11}; signs are +1 after M
        acc[12] += psum - 2.f * pg0;
        acc[13] += psum - 2.f * pg1;
        acc[0]  += psum - 2.f * pg2;
        acc[11] += psum - 2.f * pg3;
#pragma unroll
        for (int t = 0; t < 10; ++t) {
            float sg = ((par >> t) & 1) ? -1.f : 1.f;
            acc[1 + t] += sg * psum;
        }
    } else {
#pragma unroll
        for (int j = 0; j < 16; ++j)
            *(float2*)(stb + (base ^ (Pd.comboS[j] << 3))) = v[j];
        // wave-closed pairing: barrier only at end of each (even,odd) pair.
        if constexpr ((Pi & 1) != 0) __syncthreads();
    }
}

template<int... I>
__device__ __forceinline__ void run_all(std::integer_sequence<int, I...>,
                                        float2* st, const float (*tabG)[6][2], const float (*tabRZ)[14],
                                        const unsigned* comb, float* acc)
{
    (run_pass<I>(st, tabG, tabRZ, comb[I], acc), ...);
}

// ---------------- main kernel ----------------
__global__ __launch_bounds__(THREADS)
void qsim_kernel(const float* __restrict__ inputs,
                 const float* __restrict__ weights,
                 float* __restrict__ out)
{
    __shared__ float2 st[NST];           // 128 KiB state
    __shared__ float  tab[256];          // product-state init tables
    __shared__ float  tabG[20][6][2];    // uniform gate (c,s) per pass/slot
    __shared__ float  tabRZ[4][14];      // RZ half-angles per block
    __shared__ float  red[THREADS / 64][NQ];

    const int b = blockIdx.x;
    const int tid = threadIdx.x;

    // ---- per-pass combined (base | parity) words, from compile-time LUTs ----
    unsigned comb[20];
#pragma unroll
    for (int p = 0; p < 20; ++p)
        comb[p] = cLUTS.v[p][0][tid & 31] ^ cLUTS.v[p][1][tid >> 5];

    // ---- build trig + product tables (disjoint thread ranges) ----
    if (tid < 120) {
        int p = tid / 6, sl = tid - p * 6;
        float w = weights[GW.w[p][sl]];
        float s, c; __sincosf(0.5f * w, &s, &c);
        tabG[p][sl][0] = c; tabG[p][sl][1] = s;
    } else if (tid >= 128 && tid < 128 + 56) {
        int idx = tid - 128;
        int blk = idx / 14, k = idx - blk * 14;
        unsigned wi = (k < 10) ? A.rz[blk].widx_ng[k] : A.rz[blk].widx_g[k - 10];
        tabRZ[blk][k] = 0.5f * weights[wi];
    } else if (tid >= 256 && tid < 512) {
        int t = tid - 256;
        int half = t >> 7, tt = t & 127;
        float prod = 1.f;
#pragma unroll
        for (int j = 0; j < 7; ++j) {
            int xb = j + 7 * half;
            int q  = 13 - xb;
            float a = 0.5f * (inputs[b * NQ + q] + weights[q]);   // init RY ∘ blk0 RY fold
            float s, c; __sincosf(a, &s, &c);
            prod *= ((tt >> j) & 1) ? s : c;
        }
        tab[t] = prod;
    }
    __syncthreads();

    // ---- write product state ----
#pragma unroll
    for (int j = 0; j < 16; ++j) {
        int x = tid + j * THREADS;
        st[swz(x)] = make_float2(tab[x & 127] * tab[128 + (x >> 7)], 0.f);
    }
    __syncthreads();

    float acc[NQ];
#pragma unroll
    for (int q = 0; q < NQ; ++q) acc[q] = 0.f;

    run_all(std::make_integer_sequence<int, 20>{}, st, tabG, tabRZ, comb, acc);

    // ---- block-wide reduction ----
#pragma unroll
    for (int q = 0; q < NQ; ++q) {
        float v2 = acc[q];
        v2 += __shfl_down(v2, 32);
        v2 += __shfl_down(v2, 16);
        v2 += __shfl_down(v2, 8);
        v2 += __shfl_down(v2, 4);
        v2 += __shfl_down(v2, 2);
        v2 += __shfl_down(v2, 1);
        acc[q] = v2;
    }
    const int wave = tid >> 6, lane = tid & 63;
    if (lane == 0) {
#pragma unroll
        for (int q = 0; q < NQ; ++q) red[wave][q] = acc[q];
    }
    __syncthreads();
    if (tid < NQ) {
        float v2 = 0.f;
#pragma unroll
        for (int w = 0; w < THREADS / 64; ++w) v2 += red[w][tid];
        out[b * NQ + tid] = v2;
    }
}

extern "C" void kernel_launch(void* const* d_in, const int* in_sizes, int n_in,
                              void* d_out, int out_size, void* d_ws, size_t ws_size,
                              hipStream_t stream) {
    const float* inputs  = (const float*)d_in[0];
    const float* weights = (const float*)d_in[1];
    float* out = (float*)d_out;
    const int B = in_sizes[0] / NQ;   // 256
    qsim_kernel<<<dim3(B), dim3(THREADS), 0, stream>>>(inputs, weights, out);
}

// Round 7
// 61.453 us; speedup vs baseline: 1.1421x; 1.1421x over previous
//
#include <hip/hip_runtime.h>
#include <utility>

#define NQ 14
#define NST (1 << NQ)      // 16384
#define THREADS 1024

// ---------------- compile-time schedule ----------------
struct PassD {
    unsigned short comboS[16];  // pre-swizzled xor offsets (element units)
    unsigned short rows[4];     // R row (base-parity mask) per tile bit
    unsigned short tmask[4];    // C column (tile span mask) per tile bit
    unsigned short crx_widx[3]; // CRX gate weight indices (chain at tile bits g,g+1)
    unsigned short ry_widx[3];  // folded next-block RY weight indices
    unsigned char  ry_tb[3];    // tile bit each folded RY acts on
    unsigned char  ncrx;        // 2 or 3
    unsigned char  nry;         // 0..3
    short          rzidx;       // >=0: fold RZ layer before CRX chain
    unsigned char  measfold;    // 1: fold measurement, skip store
};
struct RZD  { unsigned short rows_ng[10]; unsigned short widx_ng[10]; unsigned short widx_g[4]; };
struct AllD { PassD pass[20]; RZD rz[4]; unsigned short meas_rows_ng[10]; int npass; };

__host__ __device__ constexpr int swz(int i) { return i ^ ((((i >> 1) ^ (i >> 3) ^ (i >> 5))) & 31); }

constexpr void fill_geom(PassD& P, const unsigned short* R, const unsigned short* C, const int* tb)
{
    for (int i = 0; i < 4; ++i) { P.tmask[i] = C[tb[i]]; P.rows[i] = R[tb[i]]; }
    for (int j = 0; j < 16; ++j) {
        unsigned short x = 0;
        for (int i = 0; i < 4; ++i) if ((j >> i) & 1) x = (unsigned short)(x ^ P.tmask[i]);
        P.comboS[j] = (unsigned short)swz(x);
    }
}

constexpr void ring(unsigned short* R, unsigned short* C) {
    for (int q = 0; q < NQ; ++q) {
        int cb = 13 - q, tb = 13 - ((q + 1) % NQ);
        R[tb] = (unsigned short)(R[tb] ^ R[cb]);
        C[cb] = (unsigned short)(C[cb] ^ C[tb]);
    }
}

constexpr AllD build_desc() {
    AllD A{};
    unsigned short R[NQ] = {}, C[NQ] = {};
    for (int k = 0; k < NQ; ++k) { R[k] = (unsigned short)(1u << k); C[k] = (unsigned short)(1u << k); }
    int np = 0;
    const int tiles[5][4] = {{13,12,11,10},{10,9,8,7},{7,6,5,4},{4,3,2,1},{1,0,13,2}};
    const int gfirst[5]   = {0, 3, 6, 9, 12};
    const int ngate[5]    = {3, 3, 3, 3, 2};
    const int rybits[5][3]= {{11,12,0},{10,9,8},{7,6,5},{4,3,2},{13,1,0}};
    const int nryp[5]     = {2, 3, 3, 3, 3};

    for (int blk = 0; blk < 4; ++blk) {
        ring(R, C);   // CNOT ring = pure relabeling
        for (int pi = 0; pi < 5; ++pi) {
            PassD& P = A.pass[np];
            fill_geom(P, R, C, tiles[pi]);
            P.ncrx = (unsigned char)ngate[pi];
            for (int g = 0; g < 3; ++g)
                P.crx_widx[g] = (unsigned short)((g < ngate[pi]) ? blk*42 + 28 + gfirst[pi] + g : 0);
            if (blk < 3) {
                P.nry = (unsigned char)nryp[pi];
                for (int g = 0; g < 3; ++g) {
                    if (g < nryp[pi]) {
                        int k = rybits[pi][g];                       // state bit
                        P.ry_widx[g] = (unsigned short)((blk + 1)*42 + (13 - k));
                        int t = 0;
                        for (int i = 0; i < 4; ++i) if (tiles[pi][i] == k) t = i;
                        P.ry_tb[g] = (unsigned char)t;
                    } else { P.ry_widx[g] = 0; P.ry_tb[g] = 0; }
                }
            } else { P.nry = 0; for (int g = 0; g < 3; ++g) { P.ry_widx[g] = 0; P.ry_tb[g] = 0; } }
            P.rzidx = (short)((pi == 0) ? blk : -1);
            P.measfold = (unsigned char)((blk == 3 && pi == 4) ? 1 : 0);
            if (pi == 0) {
                RZD& Z = A.rz[blk];
                for (int i = 0; i < 4; ++i)
                    Z.widx_g[i] = (unsigned short)(blk*42 + 14 + (13 - tiles[0][i]));
                int t = 0;
                for (int q = 4; q < NQ; ++q, ++t) {
                    Z.rows_ng[t] = R[13 - q];
                    Z.widx_ng[t] = (unsigned short)(blk*42 + 14 + q);
                }
            }
            ++np;
        }
        if (blk == 3)
            for (int t = 0; t < 10; ++t) A.meas_rows_ng[t] = R[13 - (1 + t)];
    }
    A.npass = np;
    return A;
}

constexpr AllD A = build_desc();
static_assert(A.npass == 20, "expected 20 passes");

// flat gate-weight-index table (slots 0-2 CRX, 3-5 RY)
struct GWT { unsigned short w[20][6]; };
constexpr GWT build_gwt() {
    GWT g{};
    for (int p = 0; p < 20; ++p) {
        for (int s = 0; s < 3; ++s) g.w[p][s]     = A.pass[p].crx_widx[s];
        for (int s = 0; s < 3; ++s) g.w[p][3 + s] = A.pass[p].ry_widx[s];
    }
    return g;
}
constexpr GWT GW = build_gwt();

// ---------------- GF(2) machinery for wave-closed pass pairing ----------------
constexpr int parity14(unsigned v) { v ^= v >> 8; v ^= v >> 4; v ^= v >> 2; v ^= v >> 1; return (int)(v & 1); }
constexpr int lead(unsigned short v) { int b = 13; while (b > 0 && !((v >> b) & 1)) --b; return b; }

struct Span {
    unsigned short red[14]; int n;
    constexpr unsigned short reduce(unsigned short v) const {
        for (int i = 0; i < n; ++i) { int lb = lead(red[i]); if ((v >> lb) & 1) v = (unsigned short)(v ^ red[i]); }
        return v;
    }
    constexpr bool add(unsigned short v) {
        unsigned short r = reduce(v);
        if (!r) return false;
        red[n++] = r; return true;
    }
};

// entry = (swz(vec)<<3) | (parity_bits << 18)
// parity bits: 0..3 = rows[0..3]; 4..13 = rz rows_ng OR meas_rows_ng (per pass)
constexpr unsigned pack_entry(unsigned short vec, const PassD& P) {
    unsigned par = 0;
    for (int t = 0; t < 4; ++t) par |= (unsigned)parity14(vec & P.rows[t]) << t;
    if (P.rzidx >= 0)
        for (int t = 0; t < 10; ++t) par |= (unsigned)parity14(vec & A.rz[P.rzidx].rows_ng[t]) << (4 + t);
    if (P.measfold)
        for (int t = 0; t < 10; ++t) par |= (unsigned)parity14(vec & A.meas_rows_ng[t]) << (4 + t);
    return ((unsigned)swz(vec) << 3) | (par << 18);
}

struct LutsT { unsigned v[20][2][32]; int ok; };

constexpr LutsT build_luts() {
    LutsT L{};
    L.ok = 1;
    for (int k = 0; k < 10; ++k) {
        const PassD& P0 = A.pass[2*k];
        const PassD& P1 = A.pass[2*k + 1];
        // W = span(T0 ∪ T1) extended to dim 10
        Span SW{}; unsigned short Wb[10] = {}; int nw = 0;
        for (int i = 0; i < 4; ++i) if (SW.add(P0.tmask[i])) Wb[nw++] = P0.tmask[i];
        for (int i = 0; i < 4; ++i) if (nw < 10 && SW.add(P1.tmask[i])) Wb[nw++] = P1.tmask[i];
        for (int b = 0; b < 14 && nw < 10; ++b) {
            unsigned short e = (unsigned short)(1u << b);
            if (SW.add(e)) Wb[nw++] = e;
        }
        if (nw != 10) L.ok = 0;
        // wave-bit complement g[4] (shared by both passes of the pair)
        Span SG = SW; unsigned short g[4] = {}; int ngv = 0;
        for (int b = 0; b < 14 && ngv < 4; ++b) {
            unsigned short e = (unsigned short)(1u << b);
            if (SG.add(e)) g[ngv++] = e;
        }
        if (ngv != 4) L.ok = 0;
        for (int pp = 0; pp < 2; ++pp) {
            const PassD& P = (pp == 0) ? P0 : P1;
            int pidx = 2*k + pp;
            Span ST{};
            for (int i = 0; i < 4; ++i) ST.add(P.tmask[i]);
            // lane vectors: completion of T inside W
            unsigned short lane[6] = {}; int nl = 0;
            {
                Span STl = ST;
                for (int i = 0; i < 10 && nl < 6; ++i)
                    if (STl.add(Wb[i])) lane[nl++] = Wb[i];
            }
            if (nl != 6) L.ok = 0;
            // bank greedy: adjust lane[i] by tile-span elements so swz(lane)&15 reaches rank 4
            {
                Span low4{};
                for (int i = 0; i < 6; ++i) {
                    int done = 0;
                    for (int c = 0; c < 16 && !done; ++c) {
                        unsigned short cand = lane[i];
                        for (int b2 = 0; b2 < 4; ++b2) if ((c >> b2) & 1) cand = (unsigned short)(cand ^ P.tmask[b2]);
                        unsigned short l4 = (unsigned short)(swz(cand) & 15);
                        if (l4) {
                            Span tmp = low4;
                            if (tmp.add(l4)) { lane[i] = cand; low4 = tmp; done = 1; }
                        }
                    }
                }
            }
            // bijectivity check: T ∪ lane ∪ g spans F_2^14
            {
                Span SF{};
                for (int i = 0; i < 4; ++i) SF.add(P.tmask[i]);
                for (int i = 0; i < 6; ++i) if (!SF.add(lane[i])) L.ok = 0;
                for (int i = 0; i < 4; ++i) if (!SF.add(g[i])) L.ok = 0;
                if (SF.n != 14) L.ok = 0;
            }
            // emit LUTs: tid bits 0..4 -> lane[0..4]; bit5 -> lane[5]; bits6..9 -> g[0..3]
            for (int t = 0; t < 32; ++t) {
                unsigned short x = 0;
                for (int i = 0; i < 5; ++i) if ((t >> i) & 1) x = (unsigned short)(x ^ lane[i]);
                L.v[pidx][0][t] = pack_entry(x, P);
                unsigned short y = 0;
                if (t & 1) y = (unsigned short)(y ^ lane[5]);
                for (int i = 0; i < 4; ++i) if ((t >> (i + 1)) & 1) y = (unsigned short)(y ^ g[i]);
                L.v[pidx][1][t] = pack_entry(y, P);
            }
        }
    }
    return L;
}

constexpr LutsT LUTS = build_luts();
static_assert(LUTS.ok == 1, "LUT construction failed (rank check)");

__device__ __constant__ LutsT cLUTS = LUTS;

// ---------------- per-pass device code (fully constant-folded) ----------------
template<int Pi>
__device__ __forceinline__ void run_pass(float2* st, const float (*tabG)[6][2], const float (*tabRZ)[14],
                                         unsigned comb, float* acc)
{
    constexpr PassD Pd = A.pass[Pi];
    char* stb = (char*)st;
    const int base = (int)(comb & 0x1FFF8u);   // pre-swizzled byte offset
    const unsigned par = comb >> 18;           // parity bits

    float2 v[16];
#pragma unroll
    for (int j = 0; j < 16; ++j)
        v[j] = *(const float2*)(stb + (base ^ (Pd.comboS[j] << 3)));

    // ---- fused RZ layer (first pass of each block; before the CRX chain) ----
    if constexpr (Pd.rzidx >= 0) {
        float phi0 = 0.f;
#pragma unroll
        for (int t = 0; t < 10; ++t) {
            float h = tabRZ[Pd.rzidx][t];
            phi0 += ((par >> (4 + t)) & 1) ? h : -h;
        }
        float e0 = (par & 1) ? tabRZ[Pd.rzidx][10] : -tabRZ[Pd.rzidx][10];
        float e1 = ((par >> 1) & 1) ? tabRZ[Pd.rzidx][11] : -tabRZ[Pd.rzidx][11];
        float e2 = ((par >> 2) & 1) ? tabRZ[Pd.rzidx][12] : -tabRZ[Pd.rzidx][12];
        float e3 = ((par >> 3) & 1) ? tabRZ[Pd.rzidx][13] : -tabRZ[Pd.rzidx][13];
#pragma unroll
        for (int j = 0; j < 16; ++j) {
            float phi = phi0 + ((j & 1) ? -e0 : e0) + ((j & 2) ? -e1 : e1)
                             + ((j & 4) ? -e2 : e2) + ((j & 8) ? -e3 : e3);
            float s, c; __sincosf(phi, &s, &c);
            float2 a = v[j];
            v[j] = make_float2(a.x * c - a.y * s, a.y * c + a.x * s);
        }
    }

    // ---- CRX chain: gate g: control = tile bit g, target = tile bit g+1 ----
#pragma unroll
    for (int g = 0; g < Pd.ncrx; ++g) {
        float c = tabG[Pi][g][0], s = tabG[Pi][g][1];
        int bc = (int)((par >> g) & 1);
        float c0 = bc ? c : 1.f, s0 = bc ? s : 0.f;   // logical ctrl for jg==0
        float c1 = bc ? 1.f : c, s1 = bc ? 0.f : s;   // logical ctrl for jg==1
#pragma unroll
        for (int j = 0; j < 16; ++j) if (!((j >> (g + 1)) & 1)) {
            int j1 = j | (1 << (g + 1));
            float ce = ((j >> g) & 1) ? c1 : c0;
            float se = ((j >> g) & 1) ? s1 : s0;
            float2 a0 = v[j], a1 = v[j1];
            v[j]  = make_float2(ce * a0.x + se * a1.y, ce * a0.y - se * a1.x);
            v[j1] = make_float2(ce * a1.x + se * a0.y, ce * a1.y - se * a0.x);
        }
    }

    // ---- folded next-block RY gates ----
#pragma unroll
    for (int g = 0; g < Pd.nry; ++g) {
        int t = Pd.ry_tb[g];   // compile-time after unroll
        float c = tabG[Pi][3 + g][0], s0 = tabG[Pi][3 + g][1];
        float s = ((par >> t) & 1) ? -s0 : s0;
#pragma unroll
        for (int j = 0; j < 16; ++j) if (!((j >> t) & 1)) {
            int j1 = j | (1 << t);
            float2 a0 = v[j], a1 = v[j1];
            v[j]  = make_float2(c * a0.x - s * a1.x, c * a0.y - s * a1.y);
            v[j1] = make_float2(s * a0.x + c * a1.x, s * a0.y + c * a1.y);
        }
    }

    if constexpr (Pd.measfold != 0) {
        float psum = 0.f, pg0 = 0.f, pg1 = 0.f, pg2 = 0.f, pg3 = 0.f;
#pragma unroll
        for (int j = 0; j < 16; ++j) {
            float pj = v[j].x * v[j].x + v[j].y * v[j].y;
            psum += pj;
            if (j & 1) pg0 += pj;
            if (j & 2) pg1 += pj;
            if (j & 4) pg2 += pj;
            if (j & 8) pg3 += pj;
        }
        float s0 = (par & 1) ? -1.f : 1.f;
        float s1 = ((par >> 1) & 1) ? -1.f : 1.f;
        float s2 = ((par >> 2) & 1) ? -1.f : 1.f;
        float s3 = ((par >> 3) & 1) ? -1.f : 1.f;
        // tile state bits {1,0,13,2} = JAX qubits {12,13,0,11}
        acc[12] += s0 * (psum - 2.f * pg0);
        acc[13] += s1 * (psum - 2.f * pg1);
        acc[0]  += s2 * (psum - 2.f * pg2);
        acc[11] += s3 * (psum - 2.f * pg3);
#pragma unroll
        for (int t = 0; t < 10; ++t) {
            float sg = ((par >> (4 + t)) & 1) ? -1.f : 1.f;
            acc[1 + t] += sg * psum;
        }
    } else {
#pragma unroll
        for (int j = 0; j < 16; ++j)
            *(float2*)(stb + (base ^ (Pd.comboS[j] << 3))) = v[j];
        // wave-closed pairing: barrier only at end of each (even,odd) pair.
        // Within a pair the odd pass reads ONLY data written by the same wave
        // (same W-coset); per-wave DS ops execute in order -> no barrier needed.
        if constexpr ((Pi & 1) != 0) __syncthreads();
    }
}

template<int... I>
__device__ __forceinline__ void run_all(std::integer_sequence<int, I...>,
                                        float2* st, const float (*tabG)[6][2], const float (*tabRZ)[14],
                                        const unsigned* comb, float* acc)
{
    (run_pass<I>(st, tabG, tabRZ, comb[I], acc), ...);
}

// ---------------- main kernel ----------------
// LDS (134 KB) caps us at 1 block/CU = 4 waves/SIMD regardless of VGPRs, so
// declare min-waves/EU = 4 -> VGPR cap 128 (not the default-8's 64): v[16]
// alone is 32 VGPRs; the 64-cap forced remat/spill pressure.
__global__ __launch_bounds__(THREADS, 4)
void qsim_kernel(const float* __restrict__ inputs,
                 const float* __restrict__ weights,
                 float* __restrict__ out)
{
    __shared__ float2 st[NST];           // 128 KiB state
    __shared__ float  tab[256];          // product-state init tables
    __shared__ float  tabG[20][6][2];    // uniform gate (c,s) per pass/slot
    __shared__ float  tabRZ[4][14];      // RZ half-angles per block
    __shared__ float  red[THREADS / 64][NQ];

    const int b = blockIdx.x;
    const int tid = threadIdx.x;

    // ---- per-pass combined (base ^ parity) words, from compile-time LUTs ----
    unsigned comb[20];
#pragma unroll
    for (int p = 0; p < 20; ++p)
        comb[p] = cLUTS.v[p][0][tid & 31] ^ cLUTS.v[p][1][tid >> 5];

    // ---- build trig + product tables (disjoint thread ranges) ----
    if (tid < 120) {
        int p = tid / 6, sl = tid - p * 6;
        float w = weights[GW.w[p][sl]];
        float s, c; __sincosf(0.5f * w, &s, &c);
        tabG[p][sl][0] = c; tabG[p][sl][1] = s;
    } else if (tid >= 128 && tid < 128 + 56) {
        int idx = tid - 128;
        int blk = idx / 14, k = idx - blk * 14;
        unsigned wi = (k < 10) ? A.rz[blk].widx_ng[k] : A.rz[blk].widx_g[k - 10];
        tabRZ[blk][k] = 0.5f * weights[wi];
    } else if (tid >= 256 && tid < 512) {
        int t = tid - 256;
        int half = t >> 7, tt = t & 127;
        float prod = 1.f;
#pragma unroll
        for (int j = 0; j < 7; ++j) {
            int xb = j + 7 * half;
            int q  = 13 - xb;
            float a = 0.5f * (inputs[b * NQ + q] + weights[q]);   // init RY ∘ blk0 RY fold
            float s, c; __sincosf(a, &s, &c);
            prod *= ((tt >> j) & 1) ? s : c;
        }
        tab[t] = prod;
    }
    __syncthreads();

    // ---- write product state ----
#pragma unroll
    for (int j = 0; j < 16; ++j) {
        int x = tid + j * THREADS;
        st[swz(x)] = make_float2(tab[x & 127] * tab[128 + (x >> 7)], 0.f);
    }
    __syncthreads();

    float acc[NQ];
#pragma unroll
    for (int q = 0; q < NQ; ++q) acc[q] = 0.f;

    run_all(std::make_integer_sequence<int, 20>{}, st, tabG, tabRZ, comb, acc);

    // ---- block-wide reduction ----
#pragma unroll
    for (int q = 0; q < NQ; ++q) {
        float v2 = acc[q];
        v2 += __shfl_down(v2, 32);
        v2 += __shfl_down(v2, 16);
        v2 += __shfl_down(v2, 8);
        v2 += __shfl_down(v2, 4);
        v2 += __shfl_down(v2, 2);
        v2 += __shfl_down(v2, 1);
        acc[q] = v2;
    }
    const int wave = tid >> 6, lane = tid & 63;
    if (lane == 0) {
#pragma unroll
        for (int q = 0; q < NQ; ++q) red[wave][q] = acc[q];
    }
    __syncthreads();
    if (tid < NQ) {
        float v2 = 0.f;
#pragma unroll
        for (int w = 0; w < THREADS / 64; ++w) v2 += red[w][tid];
        out[b * NQ + tid] = v2;
    }
}

extern "C" void kernel_launch(void* const* d_in, const int* in_sizes, int n_in,
                              void* d_out, int out_size, void* d_ws, size_t ws_size,
                              hipStream_t stream) {
    const float* inputs  = (const float*)d_in[0];
    const float* weights = (const float*)d_in[1];
    float* out = (float*)d_out;
    const int B = in_sizes[0] / NQ;   // 256
    qsim_kernel<<<dim3(B), dim3(THREADS), 0, stream>>>(inputs, weights, out);
}

// Round 8
// 52.751 us; speedup vs baseline: 1.3305x; 1.1649x over previous
//
#include <hip/hip_runtime.h>
#include <utility>

#define NQ 14
#define NST (1 << NQ)      // 16384
#define THREADS 1024

typedef float f2 __attribute__((ext_vector_type(2)));

// ---------------- compile-time schedule ----------------
struct PassD {
    unsigned short comboS[16];  // pre-swizzled xor offsets (element units)
    unsigned short rows[4];     // R row (base-parity mask) per tile bit
    unsigned short tmask[4];    // C column (tile span mask) per tile bit
    unsigned short crx_widx[3]; // CRX gate weight indices (chain at tile bits g,g+1)
    unsigned short ry_widx[3];  // folded next-block RY weight indices
    unsigned char  ry_tb[3];    // tile bit each folded RY acts on
    unsigned char  ncrx;        // 2 or 3
    unsigned char  nry;         // 0..3
    short          rzidx;       // >=0: fold RZ layer before CRX chain
    unsigned char  measfold;    // 1: fold measurement, skip store
};
struct RZD  { unsigned short rows_ng[10]; unsigned short widx_ng[10]; unsigned short widx_g[4]; };
struct AllD { PassD pass[20]; RZD rz[4]; unsigned short meas_rows_ng[10]; int npass; };

__host__ __device__ constexpr int swz(int i) { return i ^ ((((i >> 1) ^ (i >> 3) ^ (i >> 5))) & 31); }

constexpr void fill_geom(PassD& P, const unsigned short* R, const unsigned short* C, const int* tb)
{
    for (int i = 0; i < 4; ++i) { P.tmask[i] = C[tb[i]]; P.rows[i] = R[tb[i]]; }
    for (int j = 0; j < 16; ++j) {
        unsigned short x = 0;
        for (int i = 0; i < 4; ++i) if ((j >> i) & 1) x = (unsigned short)(x ^ P.tmask[i]);
        P.comboS[j] = (unsigned short)swz(x);
    }
}

constexpr void ring(unsigned short* R, unsigned short* C) {
    for (int q = 0; q < NQ; ++q) {
        int cb = 13 - q, tb = 13 - ((q + 1) % NQ);
        R[tb] = (unsigned short)(R[tb] ^ R[cb]);
        C[cb] = (unsigned short)(C[cb] ^ C[tb]);
    }
}

constexpr AllD build_desc() {
    AllD A{};
    unsigned short R[NQ] = {}, C[NQ] = {};
    for (int k = 0; k < NQ; ++k) { R[k] = (unsigned short)(1u << k); C[k] = (unsigned short)(1u << k); }
    int np = 0;
    const int tiles[5][4] = {{13,12,11,10},{10,9,8,7},{7,6,5,4},{4,3,2,1},{1,0,13,2}};
    const int gfirst[5]   = {0, 3, 6, 9, 12};
    const int ngate[5]    = {3, 3, 3, 3, 2};
    const int rybits[5][3]= {{11,12,0},{10,9,8},{7,6,5},{4,3,2},{13,1,0}};
    const int nryp[5]     = {2, 3, 3, 3, 3};

    for (int blk = 0; blk < 4; ++blk) {
        ring(R, C);   // CNOT ring = pure relabeling
        for (int pi = 0; pi < 5; ++pi) {
            PassD& P = A.pass[np];
            fill_geom(P, R, C, tiles[pi]);
            P.ncrx = (unsigned char)ngate[pi];
            for (int g = 0; g < 3; ++g)
                P.crx_widx[g] = (unsigned short)((g < ngate[pi]) ? blk*42 + 28 + gfirst[pi] + g : 0);
            if (blk < 3) {
                P.nry = (unsigned char)nryp[pi];
                for (int g = 0; g < 3; ++g) {
                    if (g < nryp[pi]) {
                        int k = rybits[pi][g];                       // state bit
                        P.ry_widx[g] = (unsigned short)((blk + 1)*42 + (13 - k));
                        int t = 0;
                        for (int i = 0; i < 4; ++i) if (tiles[pi][i] == k) t = i;
                        P.ry_tb[g] = (unsigned char)t;
                    } else { P.ry_widx[g] = 0; P.ry_tb[g] = 0; }
                }
            } else { P.nry = 0; for (int g = 0; g < 3; ++g) { P.ry_widx[g] = 0; P.ry_tb[g] = 0; } }
            P.rzidx = (short)((pi == 0) ? blk : -1);
            P.measfold = (unsigned char)((blk == 3 && pi == 4) ? 1 : 0);
            if (pi == 0) {
                RZD& Z = A.rz[blk];
                for (int i = 0; i < 4; ++i)
                    Z.widx_g[i] = (unsigned short)(blk*42 + 14 + (13 - tiles[0][i]));
                int t = 0;
                for (int q = 4; q < NQ; ++q, ++t) {
                    Z.rows_ng[t] = R[13 - q];
                    Z.widx_ng[t] = (unsigned short)(blk*42 + 14 + q);
                }
            }
            ++np;
        }
        if (blk == 3)
            for (int t = 0; t < 10; ++t) A.meas_rows_ng[t] = R[13 - (1 + t)];
    }
    A.npass = np;
    return A;
}

constexpr AllD A = build_desc();
static_assert(A.npass == 20, "expected 20 passes");

// flat gate-weight-index table (slots 0-2 CRX, 3-5 RY)
struct GWT { unsigned short w[20][6]; };
constexpr GWT build_gwt() {
    GWT g{};
    for (int p = 0; p < 20; ++p) {
        for (int s = 0; s < 3; ++s) g.w[p][s]     = A.pass[p].crx_widx[s];
        for (int s = 0; s < 3; ++s) g.w[p][3 + s] = A.pass[p].ry_widx[s];
    }
    return g;
}
constexpr GWT GW = build_gwt();

// ---------------- GF(2) machinery for wave-closed pass pairing ----------------
constexpr int parity14(unsigned v) { v ^= v >> 8; v ^= v >> 4; v ^= v >> 2; v ^= v >> 1; return (int)(v & 1); }
constexpr int lead(unsigned short v) { int b = 13; while (b > 0 && !((v >> b) & 1)) --b; return b; }

struct Span {
    unsigned short red[14]; int n;
    constexpr unsigned short reduce(unsigned short v) const {
        for (int i = 0; i < n; ++i) { int lb = lead(red[i]); if ((v >> lb) & 1) v = (unsigned short)(v ^ red[i]); }
        return v;
    }
    constexpr bool add(unsigned short v) {
        unsigned short r = reduce(v);
        if (!r) return false;
        red[n++] = r; return true;
    }
};

// entry = (swz(vec)<<3) | (parity_bits << 18)
// parity bits: 0..3 = rows[0..3]; 4..13 = rz rows_ng OR meas_rows_ng (per pass)
constexpr unsigned pack_entry(unsigned short vec, const PassD& P) {
    unsigned par = 0;
    for (int t = 0; t < 4; ++t) par |= (unsigned)parity14(vec & P.rows[t]) << t;
    if (P.rzidx >= 0)
        for (int t = 0; t < 10; ++t) par |= (unsigned)parity14(vec & A.rz[P.rzidx].rows_ng[t]) << (4 + t);
    if (P.measfold)
        for (int t = 0; t < 10; ++t) par |= (unsigned)parity14(vec & A.meas_rows_ng[t]) << (4 + t);
    return ((unsigned)swz(vec) << 3) | (par << 18);
}

struct LutsT { unsigned v[20][2][32]; int ok; };

constexpr LutsT build_luts() {
    LutsT L{};
    L.ok = 1;
    for (int k = 0; k < 10; ++k) {
        const PassD& P0 = A.pass[2*k];
        const PassD& P1 = A.pass[2*k + 1];
        // W = span(T0 ∪ T1) extended to dim 10
        Span SW{}; unsigned short Wb[10] = {}; int nw = 0;
        for (int i = 0; i < 4; ++i) if (SW.add(P0.tmask[i])) Wb[nw++] = P0.tmask[i];
        for (int i = 0; i < 4; ++i) if (nw < 10 && SW.add(P1.tmask[i])) Wb[nw++] = P1.tmask[i];
        for (int b = 0; b < 14 && nw < 10; ++b) {
            unsigned short e = (unsigned short)(1u << b);
            if (SW.add(e)) Wb[nw++] = e;
        }
        if (nw != 10) L.ok = 0;
        // wave-bit complement g[4] (shared by both passes of the pair)
        Span SG = SW; unsigned short g[4] = {}; int ngv = 0;
        for (int b = 0; b < 14 && ngv < 4; ++b) {
            unsigned short e = (unsigned short)(1u << b);
            if (SG.add(e)) g[ngv++] = e;
        }
        if (ngv != 4) L.ok = 0;
        for (int pp = 0; pp < 2; ++pp) {
            const PassD& P = (pp == 0) ? P0 : P1;
            int pidx = 2*k + pp;
            Span ST{};
            for (int i = 0; i < 4; ++i) ST.add(P.tmask[i]);
            // lane vectors: completion of T inside W
            unsigned short lane[6] = {}; int nl = 0;
            {
                Span STl = ST;
                for (int i = 0; i < 10 && nl < 6; ++i)
                    if (STl.add(Wb[i])) lane[nl++] = Wb[i];
            }
            if (nl != 6) L.ok = 0;
            // bank greedy: adjust lane[i] by tile-span elements so swz(lane)&15 reaches rank 4
            {
                Span low4{};
                for (int i = 0; i < 6; ++i) {
                    int done = 0;
                    for (int c = 0; c < 16 && !done; ++c) {
                        unsigned short cand = lane[i];
                        for (int b2 = 0; b2 < 4; ++b2) if ((c >> b2) & 1) cand = (unsigned short)(cand ^ P.tmask[b2]);
                        unsigned short l4 = (unsigned short)(swz(cand) & 15);
                        if (l4) {
                            Span tmp = low4;
                            if (tmp.add(l4)) { lane[i] = cand; low4 = tmp; done = 1; }
                        }
                    }
                }
            }
            // bijectivity check: T ∪ lane ∪ g spans F_2^14
            {
                Span SF{};
                for (int i = 0; i < 4; ++i) SF.add(P.tmask[i]);
                for (int i = 0; i < 6; ++i) if (!SF.add(lane[i])) L.ok = 0;
                for (int i = 0; i < 4; ++i) if (!SF.add(g[i])) L.ok = 0;
                if (SF.n != 14) L.ok = 0;
            }
            // emit LUTs: tid bits 0..4 -> lane[0..4]; bit5 -> lane[5]; bits6..9 -> g[0..3]
            for (int t = 0; t < 32; ++t) {
                unsigned short x = 0;
                for (int i = 0; i < 5; ++i) if ((t >> i) & 1) x = (unsigned short)(x ^ lane[i]);
                L.v[pidx][0][t] = pack_entry(x, P);
                unsigned short y = 0;
                if (t & 1) y = (unsigned short)(y ^ lane[5]);
                for (int i = 0; i < 4; ++i) if ((t >> (i + 1)) & 1) y = (unsigned short)(y ^ g[i]);
                L.v[pidx][1][t] = pack_entry(y, P);
            }
        }
    }
    return L;
}

constexpr LutsT LUTS = build_luts();
static_assert(LUTS.ok == 1, "LUT construction failed (rank check)");

__device__ __constant__ LutsT cLUTS = LUTS;

// ---------------- per-pass device code (fully constant-folded, packed-f32 math) ----------------
template<int Pi>
__device__ __forceinline__ void run_pass(f2* st, const f2 (*tabG)[6], const float (*tabRZ)[14],
                                         unsigned comb, float* acc)
{
    constexpr PassD Pd = A.pass[Pi];
    char* stb = (char*)st;
    const int base = (int)(comb & 0x1FFF8u);   // pre-swizzled byte offset
    const unsigned par = comb >> 18;           // parity bits

    f2 v[16];
#pragma unroll
    for (int j = 0; j < 16; ++j)
        v[j] = *(const f2*)(stb + (base ^ (Pd.comboS[j] << 3)));

    // ---- fused RZ layer (first pass of each block; before the CRX chain) ----
    if constexpr (Pd.rzidx >= 0) {
        float phi0 = 0.f;
#pragma unroll
        for (int t = 0; t < 10; ++t) {
            float h = tabRZ[Pd.rzidx][t];
            phi0 += ((par >> (4 + t)) & 1) ? h : -h;
        }
        float e0 = (par & 1) ? tabRZ[Pd.rzidx][10] : -tabRZ[Pd.rzidx][10];
        float e1 = ((par >> 1) & 1) ? tabRZ[Pd.rzidx][11] : -tabRZ[Pd.rzidx][11];
        float e2 = ((par >> 2) & 1) ? tabRZ[Pd.rzidx][12] : -tabRZ[Pd.rzidx][12];
        float e3 = ((par >> 3) & 1) ? tabRZ[Pd.rzidx][13] : -tabRZ[Pd.rzidx][13];
#pragma unroll
        for (int j = 0; j < 16; ++j) {
            float phi = phi0 + ((j & 1) ? -e0 : e0) + ((j & 2) ? -e1 : e1)
                             + ((j & 4) ? -e2 : e2) + ((j & 8) ? -e3 : e3);
            float s, c; __sincosf(phi, &s, &c);
            // new = (x*c - y*s, y*c + x*s) = C*v + S*v.yx, S=(-s,s)
            f2 C = {c, c}, S = {-s, s};
            v[j] = C * v[j] + S * v[j].yx;
        }
    }

    // ---- CRX chain: gate g: control = tile bit g, target = tile bit g+1 ----
#pragma unroll
    for (int g = 0; g < Pd.ncrx; ++g) {
        f2 cs = tabG[Pi][g];
        float c = cs.x, s = cs.y;
        int bc = (int)((par >> g) & 1);
        float ce0 = bc ? c : 1.f, se0 = bc ? s : 0.f;   // logical ctrl for jg==0
        float ce1 = bc ? 1.f : c, se1 = bc ? 0.f : s;   // logical ctrl for jg==1
        f2 C0 = {ce0, ce0}, S0 = {se0, -se0};
        f2 C1 = {ce1, ce1}, S1 = {se1, -se1};
#pragma unroll
        for (int j = 0; j < 16; ++j) if (!((j >> (g + 1)) & 1)) {
            int j1 = j | (1 << (g + 1));
            // compile-time select (j is a literal after unroll)
            f2 C = ((j >> g) & 1) ? C1 : C0;
            f2 S = ((j >> g) & 1) ? S1 : S0;
            f2 a0 = v[j], a1 = v[j1];
            // RX: new0 = (c*x0 + s*y1, c*y0 - s*x1) = C*a0 + S*a1.yx
            v[j]  = C * a0 + S * a1.yx;
            v[j1] = C * a1 + S * a0.yx;
        }
    }

    // ---- folded next-block RY gates ----
#pragma unroll
    for (int g = 0; g < Pd.nry; ++g) {
        int t = Pd.ry_tb[g];   // compile-time after unroll
        f2 cs = tabG[Pi][3 + g];
        float c = cs.x, s0v = cs.y;
        float s = ((par >> t) & 1) ? -s0v : s0v;
        f2 C = {c, c}, Sv = {s, s}, NS = {-s, -s};
#pragma unroll
        for (int j = 0; j < 16; ++j) if (!((j >> t) & 1)) {
            int j1 = j | (1 << t);
            f2 a0 = v[j], a1 = v[j1];
            v[j]  = C * a0 + NS * a1;   // c*a0 - s*a1
            v[j1] = Sv * a0 + C * a1;   // s*a0 + c*a1
        }
    }

    if constexpr (Pd.measfold != 0) {
        f2 ps = {0.f, 0.f}, p0 = {0.f, 0.f}, p1 = {0.f, 0.f}, p2 = {0.f, 0.f}, p3 = {0.f, 0.f};
#pragma unroll
        for (int j = 0; j < 16; ++j) {
            f2 t2 = v[j] * v[j];
            ps += t2;
            if (j & 1) p0 += t2;
            if (j & 2) p1 += t2;
            if (j & 4) p2 += t2;
            if (j & 8) p3 += t2;
        }
        float psum = ps.x + ps.y;
        float pg0 = p0.x + p0.y, pg1 = p1.x + p1.y, pg2 = p2.x + p2.y, pg3 = p3.x + p3.y;
        float s0 = (par & 1) ? -1.f : 1.f;
        float s1 = ((par >> 1) & 1) ? -1.f : 1.f;
        float s2 = ((par >> 2) & 1) ? -1.f : 1.f;
        float s3 = ((par >> 3) & 1) ? -1.f : 1.f;
        // tile state bits {1,0,13,2} = JAX qubits {12,13,0,11}
        acc[12] += s0 * (psum - 2.f * pg0);
        acc[13] += s1 * (psum - 2.f * pg1);
        acc[0]  += s2 * (psum - 2.f * pg2);
        acc[11] += s3 * (psum - 2.f * pg3);
#pragma unroll
        for (int t = 0; t < 10; ++t) {
            float sg = ((par >> (4 + t)) & 1) ? -1.f : 1.f;
            acc[1 + t] += sg * psum;
        }
    } else {
#pragma unroll
        for (int j = 0; j < 16; ++j)
            *(f2*)(stb + (base ^ (Pd.comboS[j] << 3))) = v[j];
        // wave-closed pairing: barrier only at end of each (even,odd) pair.
        // Within a pair the odd pass reads ONLY data written by the same wave
        // (same W-coset); per-wave DS ops execute in order -> no barrier needed.
        if constexpr ((Pi & 1) != 0) __syncthreads();
    }
}

template<int... I>
__device__ __forceinline__ void run_all(std::integer_sequence<int, I...>,
                                        f2* st, const f2 (*tabG)[6], const float (*tabRZ)[14],
                                        const unsigned* comb, float* acc)
{
    (run_pass<I>(st, tabG, tabRZ, comb[I], acc), ...);
}

// ---------------- main kernel ----------------
// LDS (134 KB) caps us at 1 block/CU = 4 waves/SIMD regardless of VGPRs;
// declare min-waves/EU = 4 -> VGPR cap 128.
__global__ __launch_bounds__(THREADS, 4)
void qsim_kernel(const float* __restrict__ inputs,
                 const float* __restrict__ weights,
                 float* __restrict__ out)
{
    __shared__ f2     st[NST];           // 128 KiB state
    __shared__ float  tab[256];          // product-state init tables
    __shared__ f2     tabG[20][6];       // uniform gate (c,s) per pass/slot
    __shared__ float  tabRZ[4][14];      // RZ half-angles per block
    __shared__ float  red[THREADS / 64][NQ];

    const int b = blockIdx.x;
    const int tid = threadIdx.x;

    // ---- per-pass combined (base ^ parity) words, from compile-time LUTs ----
    unsigned comb[20];
#pragma unroll
    for (int p = 0; p < 20; ++p)
        comb[p] = cLUTS.v[p][0][tid & 31] ^ cLUTS.v[p][1][tid >> 5];

    // ---- build trig + product tables (disjoint thread ranges) ----
    if (tid < 120) {
        int p = tid / 6, sl = tid - p * 6;
        float w = weights[GW.w[p][sl]];
        float s, c; __sincosf(0.5f * w, &s, &c);
        tabG[p][sl] = (f2){c, s};
    } else if (tid >= 128 && tid < 128 + 56) {
        int idx = tid - 128;
        int blk = idx / 14, k = idx - blk * 14;
        unsigned wi = (k < 10) ? A.rz[blk].widx_ng[k] : A.rz[blk].widx_g[k - 10];
        tabRZ[blk][k] = 0.5f * weights[wi];
    } else if (tid >= 256 && tid < 512) {
        int t = tid - 256;
        int half = t >> 7, tt = t & 127;
        float prod = 1.f;
#pragma unroll
        for (int j = 0; j < 7; ++j) {
            int xb = j + 7 * half;
            int q  = 13 - xb;
            float a = 0.5f * (inputs[b * NQ + q] + weights[q]);   // init RY ∘ blk0 RY fold
            float s, c; __sincosf(a, &s, &c);
            prod *= ((tt >> j) & 1) ? s : c;
        }
        tab[t] = prod;
    }
    __syncthreads();

    // ---- write product state ----
#pragma unroll
    for (int j = 0; j < 16; ++j) {
        int x = tid + j * THREADS;
        st[swz(x)] = (f2){tab[x & 127] * tab[128 + (x >> 7)], 0.f};
    }
    __syncthreads();

    float acc[NQ];
#pragma unroll
    for (int q = 0; q < NQ; ++q) acc[q] = 0.f;

    run_all(std::make_integer_sequence<int, 20>{}, st, tabG, tabRZ, comb, acc);

    // ---- block-wide reduction ----
#pragma unroll
    for (int q = 0; q < NQ; ++q) {
        float v2 = acc[q];
        v2 += __shfl_down(v2, 32);
        v2 += __shfl_down(v2, 16);
        v2 += __shfl_down(v2, 8);
        v2 += __shfl_down(v2, 4);
        v2 += __shfl_down(v2, 2);
        v2 += __shfl_down(v2, 1);
        acc[q] = v2;
    }
    const int wave = tid >> 6, lane = tid & 63;
    if (lane == 0) {
#pragma unroll
        for (int q = 0; q < NQ; ++q) red[wave][q] = acc[q];
    }
    __syncthreads();
    if (tid < NQ) {
        float v2 = 0.f;
#pragma unroll
        for (int w = 0; w < THREADS / 64; ++w) v2 += red[w][tid];
        out[b * NQ + tid] = v2;
    }
}

extern "C" void kernel_launch(void* const* d_in, const int* in_sizes, int n_in,
                              void* d_out, int out_size, void* d_ws, size_t ws_size,
                              hipStream_t stream) {
    const float* inputs  = (const float*)d_in[0];
    const float* weights = (const float*)d_in[1];
    float* out = (float*)d_out;
    const int B = in_sizes[0] / NQ;   // 256
    qsim_kernel<<<dim3(B), dim3(THREADS), 0, stream>>>(inputs, weights, out);
}

// Round 9
// 48.701 us; speedup vs baseline: 1.4411x; 1.0832x over previous
//
#include <hip/hip_runtime.h>
#include <utility>

#define NQ 14
#define NST (1 << NQ)      // 16384
#define THREADS 1024

typedef float f2 __attribute__((ext_vector_type(2)));

// ---------------- compile-time schedule ----------------
struct PassD {
    unsigned short comboR[16];  // RAW xor offsets (element units, unswizzled)
    unsigned short rows[4];     // R row (base-parity mask) per tile bit
    unsigned short tmask[4];    // C column (tile span mask) per tile bit
    unsigned short crx_widx[3]; // CRX gate weight indices (chain at tile bits g,g+1)
    unsigned short ry_widx[3];  // folded next-block RY weight indices
    unsigned char  ry_tb[3];    // tile bit each folded RY acts on
    unsigned char  ncrx;        // 2 or 3
    unsigned char  nry;         // 0..3
    short          rzidx;       // >=0: fold RZ layer before CRX chain
    unsigned char  measfold;    // 1: fold measurement, skip store
};
struct RZD  { unsigned short rows_ng[10]; unsigned short widx_ng[10]; unsigned short widx_g[4]; };
struct AllD { PassD pass[20]; RZD rz[4]; unsigned short meas_rows_ng[10]; int npass; };

constexpr void fill_geom(PassD& P, const unsigned short* R, const unsigned short* C, const int* tb)
{
    for (int i = 0; i < 4; ++i) { P.tmask[i] = C[tb[i]]; P.rows[i] = R[tb[i]]; }
    for (int j = 0; j < 16; ++j) {
        unsigned short x = 0;
        for (int i = 0; i < 4; ++i) if ((j >> i) & 1) x = (unsigned short)(x ^ P.tmask[i]);
        P.comboR[j] = x;
    }
}

constexpr void ring(unsigned short* R, unsigned short* C) {
    for (int q = 0; q < NQ; ++q) {
        int cb = 13 - q, tb = 13 - ((q + 1) % NQ);
        R[tb] = (unsigned short)(R[tb] ^ R[cb]);
        C[cb] = (unsigned short)(C[cb] ^ C[tb]);
    }
}

constexpr AllD build_desc() {
    AllD A{};
    unsigned short R[NQ] = {}, C[NQ] = {};
    for (int k = 0; k < NQ; ++k) { R[k] = (unsigned short)(1u << k); C[k] = (unsigned short)(1u << k); }
    int np = 0;
    const int tiles[5][4] = {{13,12,11,10},{10,9,8,7},{7,6,5,4},{4,3,2,1},{1,0,13,2}};
    const int gfirst[5]   = {0, 3, 6, 9, 12};
    const int ngate[5]    = {3, 3, 3, 3, 2};
    const int rybits[5][3]= {{11,12,0},{10,9,8},{7,6,5},{4,3,2},{13,1,0}};
    const int nryp[5]     = {2, 3, 3, 3, 3};

    for (int blk = 0; blk < 4; ++blk) {
        ring(R, C);   // CNOT ring = pure relabeling
        for (int pi = 0; pi < 5; ++pi) {
            PassD& P = A.pass[np];
            fill_geom(P, R, C, tiles[pi]);
            P.ncrx = (unsigned char)ngate[pi];
            for (int g = 0; g < 3; ++g)
                P.crx_widx[g] = (unsigned short)((g < ngate[pi]) ? blk*42 + 28 + gfirst[pi] + g : 0);
            if (blk < 3) {
                P.nry = (unsigned char)nryp[pi];
                for (int g = 0; g < 3; ++g) {
                    if (g < nryp[pi]) {
                        int k = rybits[pi][g];                       // state bit
                        P.ry_widx[g] = (unsigned short)((blk + 1)*42 + (13 - k));
                        int t = 0;
                        for (int i = 0; i < 4; ++i) if (tiles[pi][i] == k) t = i;
                        P.ry_tb[g] = (unsigned char)t;
                    } else { P.ry_widx[g] = 0; P.ry_tb[g] = 0; }
                }
            } else { P.nry = 0; for (int g = 0; g < 3; ++g) { P.ry_widx[g] = 0; P.ry_tb[g] = 0; } }
            P.rzidx = (short)((pi == 0) ? blk : -1);
            P.measfold = (unsigned char)((blk == 3 && pi == 4) ? 1 : 0);
            if (pi == 0) {
                RZD& Z = A.rz[blk];
                for (int i = 0; i < 4; ++i)
                    Z.widx_g[i] = (unsigned short)(blk*42 + 14 + (13 - tiles[0][i]));
                int t = 0;
                for (int q = 4; q < NQ; ++q, ++t) {
                    Z.rows_ng[t] = R[13 - q];
                    Z.widx_ng[t] = (unsigned short)(blk*42 + 14 + q);
                }
            }
            ++np;
        }
        if (blk == 3)
            for (int t = 0; t < 10; ++t) A.meas_rows_ng[t] = R[13 - (1 + t)];
    }
    A.npass = np;
    return A;
}

constexpr AllD A = build_desc();
static_assert(A.npass == 20, "expected 20 passes");

constexpr int parity14(unsigned v) { v ^= v >> 8; v ^= v >> 4; v ^= v >> 2; v ^= v >> 1; return (int)(v & 1); }

// R/C duality: parity(rows[i] & tmask[j]) == delta_ij  (basis of the M-projection)
constexpr bool check_dual() {
    for (int p = 0; p < 20; ++p)
        for (int i = 0; i < 4; ++i)
            for (int j = 0; j < 4; ++j)
                if (parity14((unsigned)(A.pass[p].rows[i] & A.pass[p].tmask[j])) != (i == j ? 1 : 0))
                    return false;
    return true;
}
static_assert(check_dual(), "R/C duality violated");

// flat gate-weight-index table (slots 0-2 CRX, 3-5 RY)
struct GWT { unsigned short w[20][6]; };
constexpr GWT build_gwt() {
    GWT g{};
    for (int p = 0; p < 20; ++p) {
        for (int s = 0; s < 3; ++s) g.w[p][s]     = A.pass[p].crx_widx[s];
        for (int s = 0; s < 3; ++s) g.w[p][3 + s] = A.pass[p].ry_widx[s];
    }
    return g;
}
constexpr GWT GW = build_gwt();

// ---------------- GF(2) machinery ----------------
constexpr int lead(unsigned short v) { int b = 13; while (b > 0 && !((v >> b) & 1)) --b; return b; }

struct Span {
    unsigned short red[14]; int n;
    constexpr unsigned short reduce(unsigned short v) const {
        for (int i = 0; i < n; ++i) { int lb = lead(red[i]); if ((v >> lb) & 1) v = (unsigned short)(v ^ red[i]); }
        return v;
    }
    constexpr bool add(unsigned short v) {
        unsigned short r = reduce(v);
        if (!r) return false;
        red[n++] = r; return true;
    }
};

// M-projection: canonical coset representative (zeros all 4 tile parities).
constexpr unsigned short proj(unsigned short vec, const PassD& P) {
    unsigned short r = vec;
    for (int t = 0; t < 4; ++t)
        if (parity14((unsigned)(vec & P.rows[t]))) r = (unsigned short)(r ^ P.tmask[t]);
    return r;
}

// ---- lane/wave vector construction (wave-closed pairing, no greedy) ----
struct VecsT { unsigned short lane[20][6]; unsigned short g[10][4]; int ok; };
constexpr VecsT build_vecs() {
    VecsT V{}; V.ok = 1;
    for (int k = 0; k < 10; ++k) {
        const PassD& P0 = A.pass[2*k];
        const PassD& P1 = A.pass[2*k + 1];
        Span SW{}; unsigned short Wb[10] = {}; int nw = 0;
        for (int i = 0; i < 4; ++i) if (SW.add(P0.tmask[i])) Wb[nw++] = P0.tmask[i];
        for (int i = 0; i < 4; ++i) if (nw < 10 && SW.add(P1.tmask[i])) Wb[nw++] = P1.tmask[i];
        for (int b = 0; b < 14 && nw < 10; ++b) {
            unsigned short e = (unsigned short)(1u << b);
            if (SW.add(e)) Wb[nw++] = e;
        }
        if (nw != 10) V.ok = 0;
        Span SG = SW; int ngv = 0;
        for (int b = 0; b < 14 && ngv < 4; ++b) {
            unsigned short e = (unsigned short)(1u << b);
            if (SG.add(e)) V.g[k][ngv++] = e;
        }
        if (ngv != 4) V.ok = 0;
        for (int pp = 0; pp < 2; ++pp) {
            const PassD& P = (pp == 0) ? P0 : P1;
            int pidx = 2*k + pp;
            Span ST{};
            for (int i = 0; i < 4; ++i) ST.add(P.tmask[i]);
            int nl = 0;
            for (int i = 0; i < 10 && nl < 6; ++i)
                if (ST.add(Wb[i])) V.lane[pidx][nl++] = Wb[i];
            if (nl != 6) V.ok = 0;
            Span SF{};
            for (int i = 0; i < 4; ++i) SF.add(P.tmask[i]);
            for (int i = 0; i < 6; ++i) if (!SF.add(V.lane[pidx][i])) V.ok = 0;
            for (int i = 0; i < 4; ++i) if (!SF.add(V.g[k][i])) V.ok = 0;
            if (SF.n != 14) V.ok = 0;
        }
    }
    return V;
}
constexpr VecsT VC = build_vecs();
static_assert(VC.ok == 1, "vec construction failed");

// projected lane basis per pass (the per-wave address-set generators)
struct P6T { unsigned short u[20][6]; };
constexpr P6T build_p6() {
    P6T X{};
    for (int p = 0; p < 20; ++p)
        for (int i = 0; i < 6; ++i)
            X.u[p][i] = proj(VC.lane[p][i], A.pass[p]);
    return X;
}
constexpr P6T P6 = build_p6();

// ---- compile-time search for bank map L' : F2^14 -> F2^4 ----
// requirements: (a) L'|low4 invertible (=> swz2 bijective);
//               (b) rank(L'|V6_p) == 4 for all passes (=> round-5-level conflicts)
constexpr unsigned lmap(const unsigned short* row, unsigned x) {
    unsigned l = 0;
    for (int t = 0; t < 4; ++t) l |= (unsigned)parity14(row[t] & x) << t;
    return l;
}
constexpr int nib_rank(const unsigned* nibs, int n) {
    unsigned basis[4] = {};
    int r = 0;
    for (int i = 0; i < n; ++i) {
        unsigned v = nibs[i] & 15u;
        for (int b = 3; b >= 0 && v; --b) {
            if (!((v >> b) & 1)) continue;
            if (basis[b]) v ^= basis[b];
            else { basis[b] = v; ++r; v = 0; }
        }
    }
    return r;
}
struct Lp { unsigned short row[4]; int score; };
constexpr Lp search_stage(unsigned seed, int iters) {
    Lp best{}; best.score = -1;
    unsigned s = seed;
    for (int it = 0; it < iters; ++it) {
        unsigned short r[4] = {};
        for (int t = 0; t < 4; ++t) { s = s*1664525u + 1013904223u; r[t] = (unsigned short)((s >> 9) & 0x3FFF); }
        unsigned cn[4] = {};
        for (int c = 0; c < 4; ++c) {
            unsigned v = 0;
            for (int t = 0; t < 4; ++t) v |= ((unsigned)(r[t] >> c) & 1u) << t;
            cn[c] = v;
        }
        if (nib_rank(cn, 4) != 4) continue;
        int sc = 0;
        for (int p = 0; p < 20; ++p) {
            unsigned im[6] = {};
            for (int i = 0; i < 6; ++i) im[i] = lmap(r, P6.u[p][i]);
            if (nib_rank(im, 6) != 4) break;
            ++sc;
        }
        if (sc > best.score) { best.score = sc; for (int t = 0; t < 4; ++t) best.row[t] = r[t]; }
        if (best.score == 20) break;
    }
    return best;
}
constexpr Lp S0 = search_stage(0x12345u, 500);
constexpr Lp S1 = search_stage(0xBEEF1u, 500);
constexpr Lp S2 = search_stage(0xC0FFEu, 500);
constexpr Lp S3 = search_stage(0x777A1u, 500);
constexpr Lp S4 = search_stage(0x51DE5u, 500);
constexpr Lp S5 = search_stage(0xA11CEu, 500);
constexpr Lp pick_best() {
    Lp b = S0;
    if (S1.score > b.score) b = S1;
    if (S2.score > b.score) b = S2;
    if (S3.score > b.score) b = S3;
    if (S4.score > b.score) b = S4;
    if (S5.score > b.score) b = S5;
    return b;
}
constexpr Lp LSEL = pick_best();
static_assert(LSEL.score >= 17, "bank-map search failed badly");

// new swizzle: high 10 bits identity, low 4 bits = L'(x)
constexpr unsigned short swz2(unsigned short x) {
    return (unsigned short)(((unsigned)x & ~15u) | lmap(LSEL.row, x));
}

// pre-swizzled combo offsets
struct CS2 { unsigned short c[20][16]; };
constexpr CS2 build_cs2() {
    CS2 C{};
    for (int p = 0; p < 20; ++p)
        for (int j = 0; j < 16; ++j)
            C.c[p][j] = swz2(A.pass[p].comboR[j]);
    return C;
}
constexpr CS2 CSS = build_cs2();

// L'(j*1024) for the init write
struct LJt { unsigned short v[16]; };
constexpr LJt build_lj() {
    LJt t{};
    for (int j = 0; j < 16; ++j) t.v[j] = (unsigned short)lmap(LSEL.row, (unsigned)(j * 1024));
    return t;
}
constexpr LJt LJ = build_lj();

// entry = (swz2(proj(vec))<<3) | (nongroup_parity_bits << 22)
constexpr unsigned pack_entry(unsigned short vec0, int p) {
    const PassD& P = A.pass[p];
    unsigned short vec = proj(vec0, P);
    unsigned par = 0;
    if (P.rzidx >= 0)
        for (int t = 0; t < 10; ++t) par |= (unsigned)parity14(vec & A.rz[P.rzidx].rows_ng[t]) << t;
    if (P.measfold)
        for (int t = 0; t < 10; ++t) par |= (unsigned)parity14(vec & A.meas_rows_ng[t]) << t;
    return ((unsigned)swz2(vec) << 3) | (par << 22);
}

struct LutsT { unsigned v[20][2][32]; };
constexpr LutsT build_luts() {
    LutsT L{};
    for (int p = 0; p < 20; ++p) {
        int k = p >> 1;
        for (int t = 0; t < 32; ++t) {
            unsigned short x = 0;
            for (int i = 0; i < 5; ++i) if ((t >> i) & 1) x = (unsigned short)(x ^ VC.lane[p][i]);
            L.v[p][0][t] = pack_entry(x, p);
            unsigned short y = 0;
            if (t & 1) y = (unsigned short)(y ^ VC.lane[p][5]);
            for (int i = 0; i < 4; ++i) if ((t >> (i + 1)) & 1) y = (unsigned short)(y ^ VC.g[k][i]);
            L.v[p][1][t] = pack_entry(y, p);
        }
    }
    return L;
}
constexpr LutsT LUTS = build_luts();
__device__ __constant__ LutsT cLUTS = LUTS;

// ---------------- per-pass device code (canonical labels, packed-f32) ----------------
template<int Pi>
__device__ __forceinline__ void run_pass(f2* st, const f2 (*tabG)[6], const float (*tabRZ)[14],
                                         unsigned comb, float* acc)
{
    constexpr PassD Pd = A.pass[Pi];
    char* stb = (char*)st;
    const int base = (int)(comb & 0x1FFF8u);   // pre-swizzled byte offset (canonical rep)
    const unsigned par = comb >> 22;           // non-group parity bits (RZ/meas passes only)

    f2 v[16];
#pragma unroll
    for (int j = 0; j < 16; ++j)
        v[j] = *(const f2*)(stb + (base ^ (CSS.c[Pi][j] << 3)));

    // ---- fused RZ layer: group-qubit signs are the tile index bits (compile-time) ----
    if constexpr (Pd.rzidx >= 0) {
        float phi0 = 0.f;
#pragma unroll
        for (int t = 0; t < 10; ++t) {
            float h = tabRZ[Pd.rzidx][t];
            phi0 += ((par >> t) & 1) ? h : -h;
        }
        const float h0 = tabRZ[Pd.rzidx][10], h1 = tabRZ[Pd.rzidx][11];
        const float h2 = tabRZ[Pd.rzidx][12], h3 = tabRZ[Pd.rzidx][13];
#pragma unroll
        for (int j = 0; j < 16; ++j) {
            float phi = ((((phi0 + ((j & 1) ? h0 : -h0)) + ((j & 2) ? h1 : -h1))
                                 + ((j & 4) ? h2 : -h2)) + ((j & 8) ? h3 : -h3));
            float s, c; __sincosf(phi, &s, &c);
            f2 C = {c, c}, S = {-s, s};
            v[j] = C * v[j] + S * v[j].yx;
        }
    }

    // ---- CRX chain: canonical -> only the 4 truly-active pairs per gate ----
#pragma unroll
    for (int g = 0; g < Pd.ncrx; ++g) {
        f2 cs = tabG[Pi][g];
        f2 C = {cs.x, cs.x}, S = {cs.y, -cs.y};
#pragma unroll
        for (int j = 0; j < 16; ++j) if (((j >> g) & 1) && !((j >> (g + 1)) & 1)) {
            int j1 = j | (1 << (g + 1));
            f2 a0 = v[j], a1 = v[j1];
            v[j]  = C * a0 + S * a1.yx;
            v[j1] = C * a1 + S * a0.yx;
        }
    }

    // ---- folded next-block RY gates (no sign select) ----
#pragma unroll
    for (int g = 0; g < Pd.nry; ++g) {
        int t = Pd.ry_tb[g];   // compile-time after unroll
        f2 cs = tabG[Pi][3 + g];
        f2 C = {cs.x, cs.x}, Sv = {cs.y, cs.y}, NS = {-cs.y, -cs.y};
#pragma unroll
        for (int j = 0; j < 16; ++j) if (!((j >> t) & 1)) {
            int j1 = j | (1 << t);
            f2 a0 = v[j], a1 = v[j1];
            v[j]  = C * a0 + NS * a1;
            v[j1] = Sv * a0 + C * a1;
        }
    }

    if constexpr (Pd.measfold != 0) {
        f2 ps = {0.f, 0.f}, p0 = {0.f, 0.f}, p1 = {0.f, 0.f}, p2 = {0.f, 0.f}, p3 = {0.f, 0.f};
#pragma unroll
        for (int j = 0; j < 16; ++j) {
            f2 t2 = v[j] * v[j];
            ps += t2;
            if (j & 1) p0 += t2;
            if (j & 2) p1 += t2;
            if (j & 4) p2 += t2;
            if (j & 8) p3 += t2;
        }
        float psum = ps.x + ps.y;
        float pg0 = p0.x + p0.y, pg1 = p1.x + p1.y, pg2 = p2.x + p2.y, pg3 = p3.x + p3.y;
        // tile state bits {1,0,13,2} = JAX qubits {12,13,0,11}; group signs +1 (canonical)
        acc[12] += psum - 2.f * pg0;
        acc[13] += psum - 2.f * pg1;
        acc[0]  += psum - 2.f * pg2;
        acc[11] += psum - 2.f * pg3;
#pragma unroll
        for (int t = 0; t < 10; ++t) {
            float sg = ((par >> t) & 1) ? -1.f : 1.f;
            acc[1 + t] += sg * psum;
        }
    } else {
#pragma unroll
        for (int j = 0; j < 16; ++j)
            *(f2*)(stb + (base ^ (CSS.c[Pi][j] << 3))) = v[j];
        // wave-closed pairing: barrier only at end of each (even,odd) pair.
        if constexpr ((Pi & 1) != 0) __syncthreads();
    }
}

template<int... I>
__device__ __forceinline__ void run_all(std::integer_sequence<int, I...>,
                                        f2* st, const f2 (*tabG)[6], const float (*tabRZ)[14],
                                        const unsigned* comb, float* acc)
{
    (run_pass<I>(st, tabG, tabRZ, comb[I], acc), ...);
}

// ---------------- main kernel ----------------
__global__ __launch_bounds__(THREADS, 4)
void qsim_kernel(const float* __restrict__ inputs,
                 const float* __restrict__ weights,
                 float* __restrict__ out)
{
    __shared__ f2     st[NST];           // 128 KiB state
    __shared__ float  tab[256];          // product-state init tables
    __shared__ f2     tabG[20][6];       // uniform gate (c,s) per pass/slot
    __shared__ float  tabRZ[4][14];      // RZ half-angles per block
    __shared__ float  red[THREADS / 64][NQ];

    const int b = blockIdx.x;
    const int tid = threadIdx.x;

    // ---- per-pass combined (base | parity) words, from compile-time LUTs ----
    unsigned comb[20];
#pragma unroll
    for (int p = 0; p < 20; ++p)
        comb[p] = cLUTS.v[p][0][tid & 31] ^ cLUTS.v[p][1][tid >> 5];

    // ---- build trig + product tables (disjoint thread ranges) ----
    if (tid < 120) {
        int p = tid / 6, sl = tid - p * 6;
        float w = weights[GW.w[p][sl]];
        float s, c; __sincosf(0.5f * w, &s, &c);
        tabG[p][sl] = (f2){c, s};
    } else if (tid >= 128 && tid < 128 + 56) {
        int idx = tid - 128;
        int blk = idx / 14, k = idx - blk * 14;
        unsigned wi = (k < 10) ? A.rz[blk].widx_ng[k] : A.rz[blk].widx_g[k - 10];
        tabRZ[blk][k] = 0.5f * weights[wi];
    } else if (tid >= 256 && tid < 512) {
        int t = tid - 256;
        int half = t >> 7, tt = t & 127;
        float prod = 1.f;
#pragma unroll
        for (int j = 0; j < 7; ++j) {
            int xb = j + 7 * half;
            int q  = 13 - xb;
            float a = 0.5f * (inputs[b * NQ + q] + weights[q]);   // init RY ∘ blk0 RY fold
            float s, c; __sincosf(a, &s, &c);
            prod *= ((tt >> j) & 1) ? s : c;
        }
        tab[t] = prod;
    }
    __syncthreads();

    // ---- write product state with swz2: L'(x) = L'(tid) ^ L'(j*1024) ----
    unsigned l4t = 0;
#pragma unroll
    for (int t = 0; t < 4; ++t)
        l4t |= (unsigned)(__popc((int)(LSEL.row[t] & tid)) & 1) << t;
#pragma unroll
    for (int j = 0; j < 16; ++j) {
        int x = tid + j * THREADS;
        int addr = (x & ~15) | (int)(l4t ^ LJ.v[j]);
        st[addr] = (f2){tab[x & 127] * tab[128 + (x >> 7)], 0.f};
    }
    __syncthreads();

    float acc[NQ];
#pragma unroll
    for (int q = 0; q < NQ; ++q) acc[q] = 0.f;

    run_all(std::make_integer_sequence<int, 20>{}, st, tabG, tabRZ, comb, acc);

    // ---- block-wide reduction ----
#pragma unroll
    for (int q = 0; q < NQ; ++q) {
        float v2 = acc[q];
        v2 += __shfl_down(v2, 32);
        v2 += __shfl_down(v2, 16);
        v2 += __shfl_down(v2, 8);
        v2 += __shfl_down(v2, 4);
        v2 += __shfl_down(v2, 2);
        v2 += __shfl_down(v2, 1);
        acc[q] = v2;
    }
    const int wave = tid >> 6, lane = tid & 63;
    if (lane == 0) {
#pragma unroll
        for (int q = 0; q < NQ; ++q) red[wave][q] = acc[q];
    }
    __syncthreads();
    if (tid < NQ) {
        float v2 = 0.f;
#pragma unroll
        for (int w = 0; w < THREADS / 64; ++w) v2 += red[w][tid];
        out[b * NQ + tid] = v2;
    }
}

extern "C" void kernel_launch(void* const* d_in, const int* in_sizes, int n_in,
                              void* d_out, int out_size, void* d_ws, size_t ws_size,
                              hipStream_t stream) {
    const float* inputs  = (const float*)d_in[0];
    const float* weights = (const float*)d_in[1];
    float* out = (float*)d_out;
    const int B = in_sizes[0] / NQ;   // 256
    qsim_kernel<<<dim3(B), dim3(THREADS), 0, stream>>>(inputs, weights, out);
}

// Round 10
// 46.474 us; speedup vs baseline: 1.5102x; 1.0479x over previous
//
#include <hip/hip_runtime.h>
#include <utility>

#define NQ 14
#define NST (1 << NQ)      // 16384
#define THREADS 1024

typedef float f2 __attribute__((ext_vector_type(2)));

// ---------------- compile-time schedule ----------------
struct PassD {
    unsigned short comboR[16];  // RAW xor offsets (element units, unswizzled)
    unsigned short rows[4];     // R row (base-parity mask) per tile bit
    unsigned short tmask[4];    // C column (tile span mask) per tile bit
    unsigned short crx_widx[3]; // CRX gate weight indices (chain at tile bits g,g+1)
    unsigned short ry_widx[3];  // folded next-block RY weight indices
    unsigned char  ry_tb[3];    // tile bit each folded RY acts on
    unsigned char  ncrx;        // 2 or 3
    unsigned char  nry;         // 0..3
    short          rzidx;       // >=0: fold RZ layer before CRX chain
    unsigned char  measfold;    // 1: fold measurement, skip store
};
struct RZD  { unsigned short rows_ng[10]; unsigned short widx_ng[10]; unsigned short widx_g[4]; };
struct AllD { PassD pass[20]; RZD rz[4]; unsigned short meas_rows_ng[10]; int npass; };

constexpr void fill_geom(PassD& P, const unsigned short* R, const unsigned short* C, const int* tb)
{
    for (int i = 0; i < 4; ++i) { P.tmask[i] = C[tb[i]]; P.rows[i] = R[tb[i]]; }
    for (int j = 0; j < 16; ++j) {
        unsigned short x = 0;
        for (int i = 0; i < 4; ++i) if ((j >> i) & 1) x = (unsigned short)(x ^ P.tmask[i]);
        P.comboR[j] = x;
    }
}

constexpr void ring(unsigned short* R, unsigned short* C) {
    for (int q = 0; q < NQ; ++q) {
        int cb = 13 - q, tb = 13 - ((q + 1) % NQ);
        R[tb] = (unsigned short)(R[tb] ^ R[cb]);
        C[cb] = (unsigned short)(C[cb] ^ C[tb]);
    }
}

constexpr AllD build_desc() {
    AllD A{};
    unsigned short R[NQ] = {}, C[NQ] = {};
    for (int k = 0; k < NQ; ++k) { R[k] = (unsigned short)(1u << k); C[k] = (unsigned short)(1u << k); }
    int np = 0;
    const int tiles[5][4] = {{13,12,11,10},{10,9,8,7},{7,6,5,4},{4,3,2,1},{1,0,13,2}};
    const int gfirst[5]   = {0, 3, 6, 9, 12};
    const int ngate[5]    = {3, 3, 3, 3, 2};
    const int rybits[5][3]= {{11,12,0},{10,9,8},{7,6,5},{4,3,2},{13,1,0}};
    const int nryp[5]     = {2, 3, 3, 3, 3};

    for (int blk = 0; blk < 4; ++blk) {
        ring(R, C);   // CNOT ring = pure relabeling
        for (int pi = 0; pi < 5; ++pi) {
            PassD& P = A.pass[np];
            fill_geom(P, R, C, tiles[pi]);
            P.ncrx = (unsigned char)ngate[pi];
            for (int g = 0; g < 3; ++g)
                P.crx_widx[g] = (unsigned short)((g < ngate[pi]) ? blk*42 + 28 + gfirst[pi] + g : 0);
            if (blk < 3) {
                P.nry = (unsigned char)nryp[pi];
                for (int g = 0; g < 3; ++g) {
                    if (g < nryp[pi]) {
                        int k = rybits[pi][g];                       // state bit
                        P.ry_widx[g] = (unsigned short)((blk + 1)*42 + (13 - k));
                        int t = 0;
                        for (int i = 0; i < 4; ++i) if (tiles[pi][i] == k) t = i;
                        P.ry_tb[g] = (unsigned char)t;
                    } else { P.ry_widx[g] = 0; P.ry_tb[g] = 0; }
                }
            } else { P.nry = 0; for (int g = 0; g < 3; ++g) { P.ry_widx[g] = 0; P.ry_tb[g] = 0; } }
            P.rzidx = (short)((pi == 0) ? blk : -1);
            P.measfold = (unsigned char)((blk == 3 && pi == 4) ? 1 : 0);
            if (pi == 0) {
                RZD& Z = A.rz[blk];
                for (int i = 0; i < 4; ++i)
                    Z.widx_g[i] = (unsigned short)(blk*42 + 14 + (13 - tiles[0][i]));
                int t = 0;
                for (int q = 4; q < NQ; ++q, ++t) {
                    Z.rows_ng[t] = R[13 - q];
                    Z.widx_ng[t] = (unsigned short)(blk*42 + 14 + q);
                }
            }
            ++np;
        }
        if (blk == 3)
            for (int t = 0; t < 10; ++t) A.meas_rows_ng[t] = R[13 - (1 + t)];
    }
    A.npass = np;
    return A;
}

constexpr AllD A = build_desc();
static_assert(A.npass == 20, "expected 20 passes");

constexpr int parity14(unsigned v) { v ^= v >> 8; v ^= v >> 4; v ^= v >> 2; v ^= v >> 1; return (int)(v & 1); }

// R/C duality: parity(rows[i] & tmask[j]) == delta_ij  (basis of the M-projection)
constexpr bool check_dual() {
    for (int p = 0; p < 20; ++p)
        for (int i = 0; i < 4; ++i)
            for (int j = 0; j < 4; ++j)
                if (parity14((unsigned)(A.pass[p].rows[i] & A.pass[p].tmask[j])) != (i == j ? 1 : 0))
                    return false;
    return true;
}
static_assert(check_dual(), "R/C duality violated");

// flat gate-weight-index table (slots 0-2 CRX, 3-5 RY)
struct GWT { unsigned short w[20][6]; };
constexpr GWT build_gwt() {
    GWT g{};
    for (int p = 0; p < 20; ++p) {
        for (int s = 0; s < 3; ++s) g.w[p][s]     = A.pass[p].crx_widx[s];
        for (int s = 0; s < 3; ++s) g.w[p][3 + s] = A.pass[p].ry_widx[s];
    }
    return g;
}
constexpr GWT GW = build_gwt();

// ---------------- GF(2) machinery ----------------
constexpr int lead(unsigned short v) { int b = 13; while (b > 0 && !((v >> b) & 1)) --b; return b; }

struct Span {
    unsigned short red[14]; int n;
    constexpr unsigned short reduce(unsigned short v) const {
        for (int i = 0; i < n; ++i) { int lb = lead(red[i]); if ((v >> lb) & 1) v = (unsigned short)(v ^ red[i]); }
        return v;
    }
    constexpr bool add(unsigned short v) {
        unsigned short r = reduce(v);
        if (!r) return false;
        red[n++] = r; return true;
    }
};

// M-projection: canonical coset representative (zeros all 4 tile parities).
constexpr unsigned short proj(unsigned short vec, const PassD& P) {
    unsigned short r = vec;
    for (int t = 0; t < 4; ++t)
        if (parity14((unsigned)(vec & P.rows[t]))) r = (unsigned short)(r ^ P.tmask[t]);
    return r;
}

// ---- lane/wave vector construction (wave-closed pairing) ----
struct VecsT { unsigned short lane[20][6]; unsigned short g[10][4]; int ok; };
constexpr VecsT build_vecs() {
    VecsT V{}; V.ok = 1;
    for (int k = 0; k < 10; ++k) {
        const PassD& P0 = A.pass[2*k];
        const PassD& P1 = A.pass[2*k + 1];
        Span SW{}; unsigned short Wb[10] = {}; int nw = 0;
        for (int i = 0; i < 4; ++i) if (SW.add(P0.tmask[i])) Wb[nw++] = P0.tmask[i];
        for (int i = 0; i < 4; ++i) if (nw < 10 && SW.add(P1.tmask[i])) Wb[nw++] = P1.tmask[i];
        for (int b = 0; b < 14 && nw < 10; ++b) {
            unsigned short e = (unsigned short)(1u << b);
            if (SW.add(e)) Wb[nw++] = e;
        }
        if (nw != 10) V.ok = 0;
        Span SG = SW; int ngv = 0;
        for (int b = 0; b < 14 && ngv < 4; ++b) {
            unsigned short e = (unsigned short)(1u << b);
            if (SG.add(e)) V.g[k][ngv++] = e;
        }
        if (ngv != 4) V.ok = 0;
        for (int pp = 0; pp < 2; ++pp) {
            const PassD& P = (pp == 0) ? P0 : P1;
            int pidx = 2*k + pp;
            Span ST{};
            for (int i = 0; i < 4; ++i) ST.add(P.tmask[i]);
            int nl = 0;
            for (int i = 0; i < 10 && nl < 6; ++i)
                if (ST.add(Wb[i])) V.lane[pidx][nl++] = Wb[i];
            if (nl != 6) V.ok = 0;
            Span SF{};
            for (int i = 0; i < 4; ++i) SF.add(P.tmask[i]);
            for (int i = 0; i < 6; ++i) if (!SF.add(V.lane[pidx][i])) V.ok = 0;
            for (int i = 0; i < 4; ++i) if (!SF.add(V.g[k][i])) V.ok = 0;
            if (SF.n != 14) V.ok = 0;
        }
    }
    return V;
}
constexpr VecsT VC = build_vecs();
static_assert(VC.ok == 1, "vec construction failed");

// projected lane basis per pass (the per-wave address-set generators)
struct P6T { unsigned short u[20][6]; };
constexpr P6T build_p6() {
    P6T X{};
    for (int p = 0; p < 20; ++p)
        for (int i = 0; i < 6; ++i)
            X.u[p][i] = proj(VC.lane[p][i], A.pass[p]);
    return X;
}
constexpr P6T P6 = build_p6();

// ---- compile-time search for bank map L' : F2^14 -> F2^4 ----
// requirements: (a) L'|low4 invertible (=> swz2 bijective);
//               (b) rank(L'|V6_p) == 4 for all passes
constexpr unsigned lmap(const unsigned short* row, unsigned x) {
    unsigned l = 0;
    for (int t = 0; t < 4; ++t) l |= (unsigned)parity14(row[t] & x) << t;
    return l;
}
constexpr int nib_rank(const unsigned* nibs, int n) {
    unsigned basis[4] = {};
    int r = 0;
    for (int i = 0; i < n; ++i) {
        unsigned v = nibs[i] & 15u;
        for (int b = 3; b >= 0 && v; --b) {
            if (!((v >> b) & 1)) continue;
            if (basis[b]) v ^= basis[b];
            else { basis[b] = v; ++r; v = 0; }
        }
    }
    return r;
}
struct Lp { unsigned short row[4]; int score; };

constexpr int full_score(const unsigned short* r) {
    unsigned cn[4] = {};
    for (int c = 0; c < 4; ++c) {
        unsigned v = 0;
        for (int t = 0; t < 4; ++t) v |= ((unsigned)(r[t] >> c) & 1u) << t;
        cn[c] = v;
    }
    if (nib_rank(cn, 4) != 4) return -1;
    int sc = 0;
    for (int p = 0; p < 20; ++p) {
        unsigned im[6] = {};
        for (int i = 0; i < 6; ++i) im[i] = lmap(r, P6.u[p][i]);
        if (nib_rank(im, 6) == 4) ++sc;
    }
    return sc;
}

constexpr Lp search_stage(unsigned seed, int iters) {
    Lp best{}; best.score = -1;
    unsigned s = seed;
    for (int it = 0; it < iters; ++it) {
        unsigned short r[4] = {};
        for (int t = 0; t < 4; ++t) { s = s*1664525u + 1013904223u; r[t] = (unsigned short)((s >> 9) & 0x3FFF); }
        unsigned cn[4] = {};
        for (int c = 0; c < 4; ++c) {
            unsigned v = 0;
            for (int t = 0; t < 4; ++t) v |= ((unsigned)(r[t] >> c) & 1u) << t;
            cn[c] = v;
        }
        if (nib_rank(cn, 4) != 4) continue;
        int sc = 0;
        for (int p = 0; p < 20; ++p) {
            unsigned im[6] = {};
            for (int i = 0; i < 6; ++i) im[i] = lmap(r, P6.u[p][i]);
            if (nib_rank(im, 6) != 4) break;
            ++sc;
        }
        if (sc > best.score) { best.score = sc; for (int t = 0; t < 4; ++t) best.row[t] = r[t]; }
        if (best.score == 20) break;
    }
    return best;
}
constexpr Lp S0 = search_stage(0x12345u, 500);
constexpr Lp S1 = search_stage(0xBEEF1u, 500);
constexpr Lp S2 = search_stage(0xC0FFEu, 500);
constexpr Lp S3 = search_stage(0x777A1u, 500);
constexpr Lp S4 = search_stage(0x51DE5u, 500);
constexpr Lp S5 = search_stage(0xA11CEu, 500);
constexpr Lp S6 = search_stage(0x0F00Du, 500);
constexpr Lp S7 = search_stage(0x9E3779u & 0xFFFFF, 500);
constexpr Lp S8 = search_stage(0x13579u, 500);
constexpr Lp S9 = search_stage(0x2468Au, 500);
constexpr Lp S10 = search_stage(0xFACE1u, 500);
constexpr Lp S11 = search_stage(0xD00D1u, 500);
constexpr Lp pick_best() {
    Lp b = S0;
    if (S1.score  > b.score) b = S1;
    if (S2.score  > b.score) b = S2;
    if (S3.score  > b.score) b = S3;
    if (S4.score  > b.score) b = S4;
    if (S5.score  > b.score) b = S5;
    if (S6.score  > b.score) b = S6;
    if (S7.score  > b.score) b = S7;
    if (S8.score  > b.score) b = S8;
    if (S9.score  > b.score) b = S9;
    if (S10.score > b.score) b = S10;
    if (S11.score > b.score) b = S11;
    return b;
}
// coordinate-descent hill climb: flip each of the 56 L' bits, keep improvements.
constexpr Lp climb(Lp start, int sweeps) {
    Lp cur = start;
    for (int sw = 0; sw < sweeps && cur.score < 20; ++sw) {
        for (int t = 0; t < 4; ++t) {
            for (int b = 0; b < 14; ++b) {
                if (cur.score >= 20) break;
                unsigned short nr[4] = {cur.row[0], cur.row[1], cur.row[2], cur.row[3]};
                nr[t] = (unsigned short)(nr[t] ^ (1u << b));
                int sc = full_score(nr);
                if (sc > cur.score) { cur.score = sc; cur.row[t] = nr[t]; }
            }
        }
    }
    return cur;
}
constexpr Lp C0 = climb(pick_best(), 2);
constexpr Lp C1 = climb(C0, 2);
constexpr Lp LSEL = C1;
static_assert(LSEL.score >= 17, "bank-map search regressed");   // monotone from round-9's >=17

// new swizzle: high 10 bits identity, low 4 bits = L'(x)
constexpr unsigned short swz2(unsigned short x) {
    return (unsigned short)(((unsigned)x & ~15u) | lmap(LSEL.row, x));
}

// ---- per-pass lane-basis canonicalization: put the slot-map kernel in lane bits 4,5 ----
// Then each 32-lane phase hits every bank-slot exactly twice (m136-free pattern).
constexpr int add_basis4(unsigned* basis, unsigned v) {
    for (int b = 3; b >= 0; --b) {
        if (!((v >> b) & 1)) continue;
        if (basis[b]) v ^= basis[b];
        else { basis[b] = v; return 1; }
    }
    return 0;
}
constexpr int add_basis6(unsigned* basis, unsigned v) {
    for (int b = 5; b >= 0; --b) {
        if (!((v >> b) & 1)) continue;
        if (basis[b]) v ^= basis[b];
        else { basis[b] = v; return 1; }
    }
    return 0;
}
struct LaneOrd { unsigned short lane[20][6]; };
constexpr LaneOrd build_lane2() {
    LaneOrd O{};
    for (int p = 0; p < 20; ++p) {
        for (int i = 0; i < 6; ++i) O.lane[p][i] = VC.lane[p][i];
        unsigned imu[6] = {};
        for (int i = 0; i < 6; ++i) imu[i] = lmap(LSEL.row, P6.u[p][i]);
        {
            unsigned chk[6] = {imu[0], imu[1], imu[2], imu[3], imu[4], imu[5]};
            if (nib_rank(chk, 6) != 4) continue;   // fallback: keep default order
        }
        unsigned short nl[6] = {};
        int ns = 0;
        unsigned ib[4] = {};   // image basis
        unsigned sb[6] = {};   // combo-space basis
        // positions 0..3: combos with independent images
        for (unsigned c = 1; c < 64 && ns < 4; ++c) {
            unsigned img = 0; unsigned short rv = 0;
            for (int i = 0; i < 6; ++i) if ((c >> i) & 1) { img ^= imu[i]; rv = (unsigned short)(rv ^ VC.lane[p][i]); }
            if (img == 0) continue;
            unsigned ib2[4] = {ib[0], ib[1], ib[2], ib[3]};
            unsigned sb2[6] = {sb[0], sb[1], sb[2], sb[3], sb[4], sb[5]};
            if (add_basis4(ib2, img) && add_basis6(sb2, c)) {
                for (int t = 0; t < 4; ++t) ib[t] = ib2[t];
                for (int t = 0; t < 6; ++t) sb[t] = sb2[t];
                nl[ns++] = rv;
            }
        }
        // positions 4,5: kernel combos (image == 0), independent in combo space
        for (unsigned c = 1; c < 64 && ns < 6; ++c) {
            unsigned img = 0; unsigned short rv = 0;
            for (int i = 0; i < 6; ++i) if ((c >> i) & 1) { img ^= imu[i]; rv = (unsigned short)(rv ^ VC.lane[p][i]); }
            if (img != 0) continue;
            unsigned sb2[6] = {sb[0], sb[1], sb[2], sb[3], sb[4], sb[5]};
            if (add_basis6(sb2, c)) {
                for (int t = 0; t < 6; ++t) sb[t] = sb2[t];
                nl[ns++] = rv;
            }
        }
        if (ns == 6)
            for (int i = 0; i < 6; ++i) O.lane[p][i] = nl[i];
    }
    return O;
}
constexpr LaneOrd LO = build_lane2();

// pre-swizzled combo offsets
struct CS2 { unsigned short c[20][16]; };
constexpr CS2 build_cs2() {
    CS2 C{};
    for (int p = 0; p < 20; ++p)
        for (int j = 0; j < 16; ++j)
            C.c[p][j] = swz2(A.pass[p].comboR[j]);
    return C;
}
constexpr CS2 CSS = build_cs2();

// L'(j*1024) for the init write
struct LJt { unsigned short v[16]; };
constexpr LJt build_lj() {
    LJt t{};
    for (int j = 0; j < 16; ++j) t.v[j] = (unsigned short)lmap(LSEL.row, (unsigned)(j * 1024));
    return t;
}
constexpr LJt LJ = build_lj();

// entry = (swz2(proj(vec))<<3) | (nongroup_parity_bits << 22)
constexpr unsigned pack_entry(unsigned short vec0, int p) {
    const PassD& P = A.pass[p];
    unsigned short vec = proj(vec0, P);
    unsigned par = 0;
    if (P.rzidx >= 0)
        for (int t = 0; t < 10; ++t) par |= (unsigned)parity14(vec & A.rz[P.rzidx].rows_ng[t]) << t;
    if (P.measfold)
        for (int t = 0; t < 10; ++t) par |= (unsigned)parity14(vec & A.meas_rows_ng[t]) << t;
    return ((unsigned)swz2(vec) << 3) | (par << 22);
}

struct LutsT { unsigned v[20][2][32]; };
constexpr LutsT build_luts() {
    LutsT L{};
    for (int p = 0; p < 20; ++p) {
        int k = p >> 1;
        for (int t = 0; t < 32; ++t) {
            unsigned short x = 0;
            for (int i = 0; i < 5; ++i) if ((t >> i) & 1) x = (unsigned short)(x ^ LO.lane[p][i]);
            L.v[p][0][t] = pack_entry(x, p);
            unsigned short y = 0;
            if (t & 1) y = (unsigned short)(y ^ LO.lane[p][5]);
            for (int i = 0; i < 4; ++i) if ((t >> (i + 1)) & 1) y = (unsigned short)(y ^ VC.g[k][i]);
            L.v[p][1][t] = pack_entry(y, p);
        }
    }
    return L;
}
constexpr LutsT LUTS = build_luts();
__device__ __constant__ LutsT cLUTS = LUTS;

// ---------------- per-pass device code (canonical labels, packed-f32) ----------------
template<int Pi>
__device__ __forceinline__ void run_pass(f2* st, const f2 (*tabG)[6], const float (*tabRZ)[14],
                                         unsigned comb, float* acc)
{
    constexpr PassD Pd = A.pass[Pi];
    char* stb = (char*)st;
    const int base = (int)(comb & 0x1FFF8u);   // pre-swizzled byte offset (canonical rep)
    const unsigned par = comb >> 22;           // non-group parity bits (RZ/meas passes only)

    f2 v[16];
#pragma unroll
    for (int j = 0; j < 16; ++j)
        v[j] = *(const f2*)(stb + (base ^ (CSS.c[Pi][j] << 3)));

    // ---- fused RZ layer: group-qubit signs are the tile index bits (compile-time) ----
    if constexpr (Pd.rzidx >= 0) {
        float phi0 = 0.f;
#pragma unroll
        for (int t = 0; t < 10; ++t) {
            float h = tabRZ[Pd.rzidx][t];
            phi0 += ((par >> t) & 1) ? h : -h;
        }
        const float h0 = tabRZ[Pd.rzidx][10], h1 = tabRZ[Pd.rzidx][11];
        const float h2 = tabRZ[Pd.rzidx][12], h3 = tabRZ[Pd.rzidx][13];
#pragma unroll
        for (int j = 0; j < 16; ++j) {
            float phi = ((((phi0 + ((j & 1) ? h0 : -h0)) + ((j & 2) ? h1 : -h1))
                                 + ((j & 4) ? h2 : -h2)) + ((j & 8) ? h3 : -h3));
            float s, c; __sincosf(phi, &s, &c);
            f2 C = {c, c}, S = {-s, s};
            v[j] = C * v[j] + S * v[j].yx;
        }
    }

    // ---- CRX chain: canonical -> only the 4 truly-active pairs per gate ----
#pragma unroll
    for (int g = 0; g < Pd.ncrx; ++g) {
        f2 cs = tabG[Pi][g];
        f2 C = {cs.x, cs.x}, S = {cs.y, -cs.y};
#pragma unroll
        for (int j = 0; j < 16; ++j) if (((j >> g) & 1) && !((j >> (g + 1)) & 1)) {
            int j1 = j | (1 << (g + 1));
            f2 a0 = v[j], a1 = v[j1];
            v[j]  = C * a0 + S * a1.yx;
            v[j1] = C * a1 + S * a0.yx;
        }
    }

    // ---- folded next-block RY gates (no sign select) ----
#pragma unroll
    for (int g = 0; g < Pd.nry; ++g) {
        int t = Pd.ry_tb[g];   // compile-time after unroll
        f2 cs = tabG[Pi][3 + g];
        f2 C = {cs.x, cs.x}, Sv = {cs.y, cs.y}, NS = {-cs.y, -cs.y};
#pragma unroll
        for (int j = 0; j < 16; ++j) if (!((j >> t) & 1)) {
            int j1 = j | (1 << t);
            f2 a0 = v[j], a1 = v[j1];
            v[j]  = C * a0 + NS * a1;
            v[j1] = Sv * a0 + C * a1;
        }
    }

    if constexpr (Pd.measfold != 0) {
        f2 ps = {0.f, 0.f}, p0 = {0.f, 0.f}, p1 = {0.f, 0.f}, p2 = {0.f, 0.f}, p3 = {0.f, 0.f};
#pragma unroll
        for (int j = 0; j < 16; ++j) {
            f2 t2 = v[j] * v[j];
            ps += t2;
            if (j & 1) p0 += t2;
            if (j & 2) p1 += t2;
            if (j & 4) p2 += t2;
            if (j & 8) p3 += t2;
        }
        float psum = ps.x + ps.y;
        float pg0 = p0.x + p0.y, pg1 = p1.x + p1.y, pg2 = p2.x + p2.y, pg3 = p3.x + p3.y;
        // tile state bits {1,0,13,2} = JAX qubits {12,13,0,11}; group signs +1 (canonical)
        acc[12] += psum - 2.f * pg0;
        acc[13] += psum - 2.f * pg1;
        acc[0]  += psum - 2.f * pg2;
        acc[11] += psum - 2.f * pg3;
#pragma unroll
        for (int t = 0; t < 10; ++t) {
            float sg = ((par >> t) & 1) ? -1.f : 1.f;
            acc[1 + t] += sg * psum;
        }
    } else {
#pragma unroll
        for (int j = 0; j < 16; ++j)
            *(f2*)(stb + (base ^ (CSS.c[Pi][j] << 3))) = v[j];
        // wave-closed pairing: barrier only at end of each (even,odd) pair.
        if constexpr ((Pi & 1) != 0) __syncthreads();
    }
}

template<int... I>
__device__ __forceinline__ void run_all(std::integer_sequence<int, I...>,
                                        f2* st, const f2 (*tabG)[6], const float (*tabRZ)[14],
                                        const unsigned* comb, float* acc)
{
    (run_pass<I>(st, tabG, tabRZ, comb[I], acc), ...);
}

// ---------------- main kernel ----------------
__global__ __launch_bounds__(THREADS, 4)
void qsim_kernel(const float* __restrict__ inputs,
                 const float* __restrict__ weights,
                 float* __restrict__ out)
{
    __shared__ f2     st[NST];           // 128 KiB state
    __shared__ float  tab[256];          // product-state init tables
    __shared__ f2     tabG[20][6];       // uniform gate (c,s) per pass/slot
    __shared__ float  tabRZ[4][14];      // RZ half-angles per block
    __shared__ float  red[THREADS / 64][NQ];

    const int b = blockIdx.x;
    const int tid = threadIdx.x;

    // ---- per-pass combined (base | parity) words, from compile-time LUTs ----
    unsigned comb[20];
#pragma unroll
    for (int p = 0; p < 20; ++p)
        comb[p] = cLUTS.v[p][0][tid & 31] ^ cLUTS.v[p][1][tid >> 5];

    // ---- build trig + product tables (disjoint thread ranges) ----
    if (tid < 120) {
        int p = tid / 6, sl = tid - p * 6;
        float w = weights[GW.w[p][sl]];
        float s, c; __sincosf(0.5f * w, &s, &c);
        tabG[p][sl] = (f2){c, s};
    } else if (tid >= 128 && tid < 128 + 56) {
        int idx = tid - 128;
        int blk = idx / 14, k = idx - blk * 14;
        unsigned wi = (k < 10) ? A.rz[blk].widx_ng[k] : A.rz[blk].widx_g[k - 10];
        tabRZ[blk][k] = 0.5f * weights[wi];
    } else if (tid >= 256 && tid < 512) {
        int t = tid - 256;
        int half = t >> 7, tt = t & 127;
        float prod = 1.f;
#pragma unroll
        for (int j = 0; j < 7; ++j) {
            int xb = j + 7 * half;
            int q  = 13 - xb;
            float a = 0.5f * (inputs[b * NQ + q] + weights[q]);   // init RY ∘ blk0 RY fold
            float s, c; __sincosf(a, &s, &c);
            prod *= ((tt >> j) & 1) ? s : c;
        }
        tab[t] = prod;
    }
    __syncthreads();

    // ---- write product state with swz2: L'(x) = L'(tid) ^ L'(j*1024) ----
    unsigned l4t = 0;
#pragma unroll
    for (int t = 0; t < 4; ++t)
        l4t |= (unsigned)(__popc((int)(LSEL.row[t] & tid)) & 1) << t;
#pragma unroll
    for (int j = 0; j < 16; ++j) {
        int x = tid + j * THREADS;
        int addr = (x & ~15) | (int)(l4t ^ LJ.v[j]);
        st[addr] = (f2){tab[x & 127] * tab[128 + (x >> 7)], 0.f};
    }
    __syncthreads();

    float acc[NQ];
#pragma unroll
    for (int q = 0; q < NQ; ++q) acc[q] = 0.f;

    run_all(std::make_integer_sequence<int, 20>{}, st, tabG, tabRZ, comb, acc);

    // ---- block-wide reduction ----
#pragma unroll
    for (int q = 0; q < NQ; ++q) {
        float v2 = acc[q];
        v2 += __shfl_down(v2, 32);
        v2 += __shfl_down(v2, 16);
        v2 += __shfl_down(v2, 8);
        v2 += __shfl_down(v2, 4);
        v2 += __shfl_down(v2, 2);
        v2 += __shfl_down(v2, 1);
        acc[q] = v2;
    }
    const int wave = tid >> 6, lane = tid & 63;
    if (lane == 0) {
#pragma unroll
        for (int q = 0; q < NQ; ++q) red[wave][q] = acc[q];
    }
    __syncthreads();
    if (tid < NQ) {
        float v2 = 0.f;
#pragma unroll
        for (int w = 0; w < THREADS / 64; ++w) v2 += red[w][tid];
        out[b * NQ + tid] = v2;
    }
}

extern "C" void kernel_launch(void* const* d_in, const int* in_sizes, int n_in,
                              void* d_out, int out_size, void* d_ws, size_t ws_size,
                              hipStream_t stream) {
    const float* inputs  = (const float*)d_in[0];
    const float* weights = (const float*)d_in[1];
    float* out = (float*)d_out;
    const int B = in_sizes[0] / NQ;   // 256
    qsim_kernel<<<dim3(B), dim3(THREADS), 0, stream>>>(inputs, weights, out);
}

// Round 11
// 42.909 us; speedup vs baseline: 1.6357x; 1.0831x over previous
//
#include <hip/hip_runtime.h>
#include <utility>

#define NQ 14
#define NST (1 << NQ)      // 16384
#define THREADS 512
#define NP 16              // passes
#define NE 32              // elements per thread (5-bit tile)

typedef float f2 __attribute__((ext_vector_type(2)));

// ---------------- compile-time schedule (5-bit tiles, 4 passes/block) ----------------
struct PassD {
    unsigned short comboR[NE];  // RAW xor offsets (element units, unswizzled)
    unsigned short rows[5];     // R row (base-parity mask) per tile bit
    unsigned short tmask[5];    // C column (tile span mask) per tile bit
    unsigned short crx_widx[4];
    unsigned short ry_widx[4];
    unsigned char  ry_tb[4];
    unsigned char  ncrx;        // 2 or 4
    unsigned char  nry;         // 0..4
    short          rzidx;
    unsigned char  measfold;
};
struct RZD  { unsigned short rows_ng[9]; unsigned short widx_ng[9]; unsigned short widx_g[5]; };
struct AllD { PassD pass[NP]; RZD rz[4]; unsigned short meas_rows_ng[9]; int npass; };

constexpr void fill_geom(PassD& P, const unsigned short* R, const unsigned short* C, const int* tb)
{
    for (int i = 0; i < 5; ++i) { P.tmask[i] = C[tb[i]]; P.rows[i] = R[tb[i]]; }
    for (int j = 0; j < NE; ++j) {
        unsigned short x = 0;
        for (int i = 0; i < 5; ++i) if ((j >> i) & 1) x = (unsigned short)(x ^ P.tmask[i]);
        P.comboR[j] = x;
    }
}

constexpr void ring(unsigned short* R, unsigned short* C) {
    for (int q = 0; q < NQ; ++q) {
        int cb = 13 - q, tb = 13 - ((q + 1) % NQ);
        R[tb] = (unsigned short)(R[tb] ^ R[cb]);
        C[cb] = (unsigned short)(C[cb] ^ C[tb]);
    }
}

constexpr AllD build_desc() {
    AllD A{};
    unsigned short R[NQ] = {}, C[NQ] = {};
    for (int k = 0; k < NQ; ++k) { R[k] = (unsigned short)(1u << k); C[k] = (unsigned short)(1u << k); }
    int np = 0;
    // 4 passes per block; chain gate g: control tile-bit g, target tile-bit g+1.
    const int tiles[4][5]  = {{13,12,11,10,9},{9,8,7,6,5},{5,4,3,2,1},{1,0,13,3,2}};
    const int gfirst[4]    = {0, 4, 8, 12};
    const int ngate[4]     = {4, 4, 4, 2};
    const int rybits[4][4] = {{12,11,10,0},{9,8,7,6},{5,4,3,2},{13,1,0,0}};
    const int nryp[4]      = {3, 4, 4, 3};

    for (int blk = 0; blk < 4; ++blk) {
        ring(R, C);   // CNOT ring = pure relabeling
        for (int pi = 0; pi < 4; ++pi) {
            PassD& P = A.pass[np];
            fill_geom(P, R, C, tiles[pi]);
            P.ncrx = (unsigned char)ngate[pi];
            for (int g = 0; g < 4; ++g)
                P.crx_widx[g] = (unsigned short)((g < ngate[pi]) ? blk*42 + 28 + gfirst[pi] + g : 0);
            if (blk < 3) {
                P.nry = (unsigned char)nryp[pi];
                for (int g = 0; g < 4; ++g) {
                    if (g < nryp[pi]) {
                        int k = rybits[pi][g];
                        P.ry_widx[g] = (unsigned short)((blk + 1)*42 + (13 - k));
                        int t = 0;
                        for (int i = 0; i < 5; ++i) if (tiles[pi][i] == k) t = i;
                        P.ry_tb[g] = (unsigned char)t;
                    } else { P.ry_widx[g] = 0; P.ry_tb[g] = 0; }
                }
            } else { P.nry = 0; for (int g = 0; g < 4; ++g) { P.ry_widx[g] = 0; P.ry_tb[g] = 0; } }
            P.rzidx = (short)((pi == 0) ? blk : -1);
            P.measfold = (unsigned char)((blk == 3 && pi == 3) ? 1 : 0);
            if (pi == 0) {
                RZD& Z = A.rz[blk];
                for (int i = 0; i < 5; ++i)
                    Z.widx_g[i] = (unsigned short)(blk*42 + 14 + (13 - tiles[0][i]));
                // non-group qubits 5..13 (state bits 8..0)
                int t = 0;
                for (int q = 5; q < NQ; ++q, ++t) {
                    Z.rows_ng[t] = R[13 - q];
                    Z.widx_ng[t] = (unsigned short)(blk*42 + 14 + q);
                }
            }
            ++np;
        }
        if (blk == 3)
            for (int t = 0; t < 9; ++t) A.meas_rows_ng[t] = R[13 - (1 + t)];  // qubits 1..9
    }
    A.npass = np;
    return A;
}

constexpr AllD A = build_desc();
static_assert(A.npass == NP, "expected 16 passes");

constexpr int parity14(unsigned v) { v ^= v >> 8; v ^= v >> 4; v ^= v >> 2; v ^= v >> 1; return (int)(v & 1); }

constexpr bool check_dual() {
    for (int p = 0; p < NP; ++p)
        for (int i = 0; i < 5; ++i)
            for (int j = 0; j < 5; ++j)
                if (parity14((unsigned)(A.pass[p].rows[i] & A.pass[p].tmask[j])) != (i == j ? 1 : 0))
                    return false;
    return true;
}
static_assert(check_dual(), "R/C duality violated");

// flat gate-weight-index table (slots 0-3 CRX, 4-7 RY)
struct GWT { unsigned short w[NP][8]; };
constexpr GWT build_gwt() {
    GWT g{};
    for (int p = 0; p < NP; ++p) {
        for (int s = 0; s < 4; ++s) g.w[p][s]     = A.pass[p].crx_widx[s];
        for (int s = 0; s < 4; ++s) g.w[p][4 + s] = A.pass[p].ry_widx[s];
    }
    return g;
}
constexpr GWT GW = build_gwt();

// ---------------- GF(2) machinery ----------------
constexpr int lead(unsigned short v) { int b = 13; while (b > 0 && !((v >> b) & 1)) --b; return b; }

struct Span {
    unsigned short red[14]; int n;
    constexpr unsigned short reduce(unsigned short v) const {
        for (int i = 0; i < n; ++i) { int lb = lead(red[i]); if ((v >> lb) & 1) v = (unsigned short)(v ^ red[i]); }
        return v;
    }
    constexpr bool add(unsigned short v) {
        unsigned short r = reduce(v);
        if (!r) return false;
        red[n++] = r; return true;
    }
};

// M-projection: canonical coset representative (zeros all 5 tile parities).
constexpr unsigned short proj(unsigned short vec, const PassD& P) {
    unsigned short r = vec;
    for (int t = 0; t < 5; ++t)
        if (parity14((unsigned)(vec & P.rows[t]))) r = (unsigned short)(r ^ P.tmask[t]);
    return r;
}

// ---- lane/wave vector construction (wave-closed pairing; tile5 + lane6 = 11 >= dim(W)) ----
struct VecsT { unsigned short lane[NP][6]; unsigned short g[NP/2][3]; int ok; };
constexpr VecsT build_vecs() {
    VecsT V{}; V.ok = 1;
    for (int k = 0; k < NP/2; ++k) {
        const PassD& P0 = A.pass[2*k];
        const PassD& P1 = A.pass[2*k + 1];
        Span SW{}; unsigned short Wb[11] = {}; int nw = 0;
        for (int i = 0; i < 5; ++i) if (SW.add(P0.tmask[i])) Wb[nw++] = P0.tmask[i];
        for (int i = 0; i < 5; ++i) if (nw < 11 && SW.add(P1.tmask[i])) Wb[nw++] = P1.tmask[i];
        for (int b = 0; b < 14 && nw < 11; ++b) {
            unsigned short e = (unsigned short)(1u << b);
            if (SW.add(e)) Wb[nw++] = e;
        }
        if (nw != 11) V.ok = 0;
        Span SG = SW; int ngv = 0;
        for (int b = 0; b < 14 && ngv < 3; ++b) {
            unsigned short e = (unsigned short)(1u << b);
            if (SG.add(e)) V.g[k][ngv++] = e;
        }
        if (ngv != 3) V.ok = 0;
        for (int pp = 0; pp < 2; ++pp) {
            const PassD& P = (pp == 0) ? P0 : P1;
            int pidx = 2*k + pp;
            Span ST{};
            for (int i = 0; i < 5; ++i) ST.add(P.tmask[i]);
            int nl = 0;
            for (int i = 0; i < 11 && nl < 6; ++i)
                if (ST.add(Wb[i])) V.lane[pidx][nl++] = Wb[i];
            if (nl != 6) V.ok = 0;
            Span SF{};
            for (int i = 0; i < 5; ++i) SF.add(P.tmask[i]);
            for (int i = 0; i < 6; ++i) if (!SF.add(V.lane[pidx][i])) V.ok = 0;
            for (int i = 0; i < 3; ++i) if (!SF.add(V.g[k][i])) V.ok = 0;
            if (SF.n != 14) V.ok = 0;
        }
    }
    return V;
}
constexpr VecsT VC = build_vecs();
static_assert(VC.ok == 1, "vec construction failed");

struct P6T { unsigned short u[NP][6]; };
constexpr P6T build_p6() {
    P6T X{};
    for (int p = 0; p < NP; ++p)
        for (int i = 0; i < 6; ++i)
            X.u[p][i] = proj(VC.lane[p][i], A.pass[p]);
    return X;
}
constexpr P6T P6 = build_p6();

// ---- bank map L' : F2^14 -> F2^4 ----
constexpr unsigned lmap(const unsigned short* row, unsigned x) {
    unsigned l = 0;
    for (int t = 0; t < 4; ++t) l |= (unsigned)parity14(row[t] & x) << t;
    return l;
}
constexpr int nib_rank(const unsigned* nibs, int n) {
    unsigned basis[4] = {};
    int r = 0;
    for (int i = 0; i < n; ++i) {
        unsigned v = nibs[i] & 15u;
        for (int b = 3; b >= 0 && v; --b) {
            if (!((v >> b) & 1)) continue;
            if (basis[b]) v ^= basis[b];
            else { basis[b] = v; ++r; v = 0; }
        }
    }
    return r;
}
struct Lp { unsigned short row[4]; int score; };

constexpr int full_score(const unsigned short* r) {
    unsigned cn[4] = {};
    for (int c = 0; c < 4; ++c) {
        unsigned v = 0;
        for (int t = 0; t < 4; ++t) v |= ((unsigned)(r[t] >> c) & 1u) << t;
        cn[c] = v;
    }
    if (nib_rank(cn, 4) != 4) return -1;
    int sc = 0;
    for (int p = 0; p < NP; ++p) {
        unsigned im[6] = {};
        for (int i = 0; i < 6; ++i) im[i] = lmap(r, P6.u[p][i]);
        if (nib_rank(im, 6) == 4) ++sc;
    }
    return sc;
}

constexpr Lp search_stage(unsigned seed, int iters) {
    Lp best{}; best.score = -1;
    unsigned s = seed;
    for (int it = 0; it < iters; ++it) {
        unsigned short r[4] = {};
        for (int t = 0; t < 4; ++t) { s = s*1664525u + 1013904223u; r[t] = (unsigned short)((s >> 9) & 0x3FFF); }
        int sc = full_score(r);
        if (sc > best.score) { best.score = sc; for (int t = 0; t < 4; ++t) best.row[t] = r[t]; }
        if (best.score == NP) break;
    }
    return best;
}
constexpr Lp S0 = search_stage(0x12345u, 400);
constexpr Lp S1 = search_stage(0xBEEF1u, 400);
constexpr Lp S2 = search_stage(0xC0FFEu, 400);
constexpr Lp S3 = search_stage(0x777A1u, 400);
constexpr Lp S4 = search_stage(0x51DE5u, 400);
constexpr Lp S5 = search_stage(0xA11CEu, 400);
constexpr Lp S6 = search_stage(0x0F00Du, 400);
constexpr Lp S7 = search_stage(0x13579u, 400);
constexpr Lp pick_best() {
    Lp b = S0;
    if (S1.score > b.score) b = S1;
    if (S2.score > b.score) b = S2;
    if (S3.score > b.score) b = S3;
    if (S4.score > b.score) b = S4;
    if (S5.score > b.score) b = S5;
    if (S6.score > b.score) b = S6;
    if (S7.score > b.score) b = S7;
    return b;
}
constexpr Lp climb(Lp start, int sweeps) {
    Lp cur = start;
    for (int sw = 0; sw < sweeps && cur.score < NP; ++sw) {
        for (int t = 0; t < 4; ++t) {
            for (int b = 0; b < 14; ++b) {
                if (cur.score >= NP) break;
                unsigned short nr[4] = {cur.row[0], cur.row[1], cur.row[2], cur.row[3]};
                nr[t] = (unsigned short)(nr[t] ^ (1u << b));
                int sc = full_score(nr);
                if (sc > cur.score) { cur.score = sc; cur.row[t] = nr[t]; }
            }
        }
    }
    return cur;
}
constexpr Lp C0 = climb(pick_best(), 2);
constexpr Lp C1 = climb(C0, 2);
constexpr Lp LSEL = C1;
static_assert(LSEL.score >= 13, "bank-map search failed badly");

constexpr unsigned short swz2(unsigned short x) {
    return (unsigned short)(((unsigned)x & ~15u) | lmap(LSEL.row, x));
}

// ---- lane-basis canonicalization: slot-map kernel -> lane bits 4,5 ----
constexpr int add_basis4(unsigned* basis, unsigned v) {
    for (int b = 3; b >= 0; --b) {
        if (!((v >> b) & 1)) continue;
        if (basis[b]) v ^= basis[b];
        else { basis[b] = v; return 1; }
    }
    return 0;
}
constexpr int add_basis6(unsigned* basis, unsigned v) {
    for (int b = 5; b >= 0; --b) {
        if (!((v >> b) & 1)) continue;
        if (basis[b]) v ^= basis[b];
        else { basis[b] = v; return 1; }
    }
    return 0;
}
struct LaneOrd { unsigned short lane[NP][6]; };
constexpr LaneOrd build_lane2() {
    LaneOrd O{};
    for (int p = 0; p < NP; ++p) {
        for (int i = 0; i < 6; ++i) O.lane[p][i] = VC.lane[p][i];
        unsigned imu[6] = {};
        for (int i = 0; i < 6; ++i) imu[i] = lmap(LSEL.row, P6.u[p][i]);
        {
            unsigned chk[6] = {imu[0], imu[1], imu[2], imu[3], imu[4], imu[5]};
            if (nib_rank(chk, 6) != 4) continue;   // fallback: keep default order
        }
        unsigned short nl[6] = {};
        int ns = 0;
        unsigned ib[4] = {};
        unsigned sb[6] = {};
        for (unsigned c = 1; c < 64 && ns < 4; ++c) {
            unsigned img = 0; unsigned short rv = 0;
            for (int i = 0; i < 6; ++i) if ((c >> i) & 1) { img ^= imu[i]; rv = (unsigned short)(rv ^ VC.lane[p][i]); }
            if (img == 0) continue;
            unsigned ib2[4] = {ib[0], ib[1], ib[2], ib[3]};
            unsigned sb2[6] = {sb[0], sb[1], sb[2], sb[3], sb[4], sb[5]};
            if (add_basis4(ib2, img) && add_basis6(sb2, c)) {
                for (int t = 0; t < 4; ++t) ib[t] = ib2[t];
                for (int t = 0; t < 6; ++t) sb[t] = sb2[t];
                nl[ns++] = rv;
            }
        }
        for (unsigned c = 1; c < 64 && ns < 6; ++c) {
            unsigned img = 0; unsigned short rv = 0;
            for (int i = 0; i < 6; ++i) if ((c >> i) & 1) { img ^= imu[i]; rv = (unsigned short)(rv ^ VC.lane[p][i]); }
            if (img != 0) continue;
            unsigned sb2[6] = {sb[0], sb[1], sb[2], sb[3], sb[4], sb[5]};
            if (add_basis6(sb2, c)) {
                for (int t = 0; t < 6; ++t) sb[t] = sb2[t];
                nl[ns++] = rv;
            }
        }
        if (ns == 6)
            for (int i = 0; i < 6; ++i) O.lane[p][i] = nl[i];
    }
    return O;
}
constexpr LaneOrd LO = build_lane2();

// pre-swizzled combo offsets
struct CS2 { unsigned short c[NP][NE]; };
constexpr CS2 build_cs2() {
    CS2 C{};
    for (int p = 0; p < NP; ++p)
        for (int j = 0; j < NE; ++j)
            C.c[p][j] = swz2(A.pass[p].comboR[j]);
    return C;
}
constexpr CS2 CSS = build_cs2();

// L'(j*512) for the init write
struct LJt { unsigned short v[NE]; };
constexpr LJt build_lj() {
    LJt t{};
    for (int j = 0; j < NE; ++j) t.v[j] = (unsigned short)lmap(LSEL.row, (unsigned)(j * THREADS));
    return t;
}
constexpr LJt LJ = build_lj();

// entry = (swz2(proj(vec))<<3) | (nongroup_parity_bits(9) << 22)
constexpr unsigned pack_entry(unsigned short vec0, int p) {
    const PassD& P = A.pass[p];
    unsigned short vec = proj(vec0, P);
    unsigned par = 0;
    if (P.rzidx >= 0)
        for (int t = 0; t < 9; ++t) par |= (unsigned)parity14(vec & A.rz[P.rzidx].rows_ng[t]) << t;
    if (P.measfold)
        for (int t = 0; t < 9; ++t) par |= (unsigned)parity14(vec & A.meas_rows_ng[t]) << t;
    return ((unsigned)swz2(vec) << 3) | (par << 22);
}

// LUT0: tid bits 0-4 (lane vecs 0-4); LUT1: tid bits 5-8 (lane vec 5 + wave g[0..2])
struct LutsT { unsigned v[NP][2][32]; };
constexpr LutsT build_luts() {
    LutsT L{};
    for (int p = 0; p < NP; ++p) {
        int k = p >> 1;
        for (int t = 0; t < 32; ++t) {
            unsigned short x = 0;
            for (int i = 0; i < 5; ++i) if ((t >> i) & 1) x = (unsigned short)(x ^ LO.lane[p][i]);
            L.v[p][0][t] = pack_entry(x, p);
        }
        for (int t = 0; t < 16; ++t) {
            unsigned short y = 0;
            if (t & 1) y = (unsigned short)(y ^ LO.lane[p][5]);
            for (int i = 0; i < 3; ++i) if ((t >> (i + 1)) & 1) y = (unsigned short)(y ^ VC.g[k][i]);
            L.v[p][1][t] = pack_entry(y, p);
        }
    }
    return L;
}
constexpr LutsT LUTS = build_luts();
__device__ __constant__ LutsT cLUTS = LUTS;

// ---------------- per-pass device code (canonical labels, packed-f32) ----------------
template<int Pi>
__device__ __forceinline__ void run_pass(f2* st, const f2 (*tabG)[8], const float (*tabRZ)[14],
                                         unsigned comb, float* acc)
{
    constexpr PassD Pd = A.pass[Pi];
    char* stb = (char*)st;
    const int base = (int)(comb & 0x1FFF8u);
    const unsigned par = comb >> 22;          // 9 non-group parity bits

    f2 v[NE];
#pragma unroll
    for (int j = 0; j < NE; ++j)
        v[j] = *(const f2*)(stb + (base ^ (CSS.c[Pi][j] << 3)));

    // ---- fused RZ layer (first pass of each block) ----
    if constexpr (Pd.rzidx >= 0) {
        float phi0 = 0.f;
#pragma unroll
        for (int t = 0; t < 9; ++t) {
            float h = tabRZ[Pd.rzidx][t];
            phi0 += ((par >> t) & 1) ? h : -h;
        }
        const float h0 = tabRZ[Pd.rzidx][9],  h1 = tabRZ[Pd.rzidx][10];
        const float h2 = tabRZ[Pd.rzidx][11], h3 = tabRZ[Pd.rzidx][12];
        const float h4 = tabRZ[Pd.rzidx][13];
#pragma unroll
        for (int j = 0; j < NE; ++j) {
            float phi = (((((phi0 + ((j & 1) ? h0 : -h0)) + ((j & 2) ? h1 : -h1))
                                  + ((j & 4) ? h2 : -h2)) + ((j & 8) ? h3 : -h3))
                                  + ((j & 16) ? h4 : -h4));
            float s, c; __sincosf(phi, &s, &c);
            f2 C = {c, c}, S = {-s, s};
            v[j] = C * v[j] + S * v[j].yx;
        }
    }

    // ---- CRX chain: control = tile bit g (logical), target = tile bit g+1 ----
#pragma unroll
    for (int g = 0; g < Pd.ncrx; ++g) {
        f2 cs = tabG[Pi][g];
        f2 C = {cs.x, cs.x}, S = {cs.y, -cs.y};
#pragma unroll
        for (int j = 0; j < NE; ++j) if (((j >> g) & 1) && !((j >> (g + 1)) & 1)) {
            int j1 = j | (1 << (g + 1));
            f2 a0 = v[j], a1 = v[j1];
            v[j]  = C * a0 + S * a1.yx;
            v[j1] = C * a1 + S * a0.yx;
        }
    }

    // ---- folded next-block RY gates ----
#pragma unroll
    for (int g = 0; g < Pd.nry; ++g) {
        int t = Pd.ry_tb[g];
        f2 cs = tabG[Pi][4 + g];
        f2 C = {cs.x, cs.x}, Sv = {cs.y, cs.y}, NS = {-cs.y, -cs.y};
#pragma unroll
        for (int j = 0; j < NE; ++j) if (!((j >> t) & 1)) {
            int j1 = j | (1 << t);
            f2 a0 = v[j], a1 = v[j1];
            v[j]  = C * a0 + NS * a1;
            v[j1] = Sv * a0 + C * a1;
        }
    }

    if constexpr (Pd.measfold != 0) {
        f2 ps = {0.f, 0.f}, p0 = {0.f, 0.f}, p1 = {0.f, 0.f}, p2 = {0.f, 0.f}, p3 = {0.f, 0.f}, p4 = {0.f, 0.f};
#pragma unroll
        for (int j = 0; j < NE; ++j) {
            f2 t2 = v[j] * v[j];
            ps += t2;
            if (j & 1)  p0 += t2;
            if (j & 2)  p1 += t2;
            if (j & 4)  p2 += t2;
            if (j & 8)  p3 += t2;
            if (j & 16) p4 += t2;
        }
        float psum = ps.x + ps.y;
        float pg0 = p0.x + p0.y, pg1 = p1.x + p1.y, pg2 = p2.x + p2.y;
        float pg3 = p3.x + p3.y, pg4 = p4.x + p4.y;
        // tile state bits {1,0,13,3,2} = JAX qubits {12,13,0,10,11}; group signs +1 (canonical)
        acc[12] += psum - 2.f * pg0;
        acc[13] += psum - 2.f * pg1;
        acc[0]  += psum - 2.f * pg2;
        acc[10] += psum - 2.f * pg3;
        acc[11] += psum - 2.f * pg4;
#pragma unroll
        for (int t = 0; t < 9; ++t) {
            float sg = ((par >> t) & 1) ? -1.f : 1.f;
            acc[1 + t] += sg * psum;
        }
    } else {
#pragma unroll
        for (int j = 0; j < NE; ++j)
            *(f2*)(stb + (base ^ (CSS.c[Pi][j] << 3))) = v[j];
        // wave-closed pairing: barrier only at end of each (even,odd) pair.
        if constexpr ((Pi & 1) != 0) __syncthreads();
    }
}

template<int... I>
__device__ __forceinline__ void run_all(std::integer_sequence<int, I...>,
                                        f2* st, const f2 (*tabG)[8], const float (*tabRZ)[14],
                                        const unsigned* comb, float* acc)
{
    (run_pass<I>(st, tabG, tabRZ, comb[I], acc), ...);
}

// ---------------- main kernel ----------------
// 512 threads, 32 elem/thread; 8 waves/CU (2/SIMD) -> VGPR cap 256 via launch_bounds.
__global__ __launch_bounds__(THREADS, 2)
void qsim_kernel(const float* __restrict__ inputs,
                 const float* __restrict__ weights,
                 float* __restrict__ out)
{
    __shared__ f2     st[NST];           // 128 KiB state
    __shared__ float  tab[256];
    __shared__ f2     tabG[NP][8];
    __shared__ float  tabRZ[4][14];      // 9 ng + 5 group half-angles
    __shared__ float  red[THREADS / 64][NQ];

    const int b = blockIdx.x;
    const int tid = threadIdx.x;

    unsigned comb[NP];
#pragma unroll
    for (int p = 0; p < NP; ++p)
        comb[p] = cLUTS.v[p][0][tid & 31] ^ cLUTS.v[p][1][tid >> 5];

    // ---- build trig + product tables (disjoint thread ranges) ----
    if (tid < 128) {
        int p = tid >> 3, sl = tid & 7;
        float w = weights[GW.w[p][sl]];
        float s, c; __sincosf(0.5f * w, &s, &c);
        tabG[p][sl] = (f2){c, s};
    } else if (tid >= 128 && tid < 128 + 56) {
        int idx = tid - 128;
        int blk = idx / 14, k = idx - blk * 14;
        unsigned wi = (k < 9) ? A.rz[blk].widx_ng[k] : A.rz[blk].widx_g[k - 9];
        tabRZ[blk][k] = 0.5f * weights[wi];
    } else if (tid >= 256) {
        int t = tid - 256;
        int half = t >> 7, tt = t & 127;
        float prod = 1.f;
#pragma unroll
        for (int j = 0; j < 7; ++j) {
            int xb = j + 7 * half;
            int q  = 13 - xb;
            float a = 0.5f * (inputs[b * NQ + q] + weights[q]);   // init RY ∘ blk0 RY fold
            float s, c; __sincosf(a, &s, &c);
            prod *= ((tt >> j) & 1) ? s : c;
        }
        tab[t] = prod;
    }
    __syncthreads();

    // ---- write product state with swz2 ----
    unsigned l4t = 0;
#pragma unroll
    for (int t = 0; t < 4; ++t)
        l4t |= (unsigned)(__popc((int)(LSEL.row[t] & tid)) & 1) << t;
#pragma unroll
    for (int j = 0; j < NE; ++j) {
        int x = tid + j * THREADS;
        int addr = (x & ~15) | (int)(l4t ^ LJ.v[j]);
        st[addr] = (f2){tab[x & 127] * tab[128 + (x >> 7)], 0.f};
    }
    __syncthreads();

    float acc[NQ];
#pragma unroll
    for (int q = 0; q < NQ; ++q) acc[q] = 0.f;

    run_all(std::make_integer_sequence<int, NP>{}, st, tabG, tabRZ, comb, acc);

    // ---- block-wide reduction ----
#pragma unroll
    for (int q = 0; q < NQ; ++q) {
        float v2 = acc[q];
        v2 += __shfl_down(v2, 32);
        v2 += __shfl_down(v2, 16);
        v2 += __shfl_down(v2, 8);
        v2 += __shfl_down(v2, 4);
        v2 += __shfl_down(v2, 2);
        v2 += __shfl_down(v2, 1);
        acc[q] = v2;
    }
    const int wave = tid >> 6, lane = tid & 63;
    if (lane == 0) {
#pragma unroll
        for (int q = 0; q < NQ; ++q) red[wave][q] = acc[q];
    }
    __syncthreads();
    if (tid < NQ) {
        float v2 = 0.f;
#pragma unroll
        for (int w = 0; w < THREADS / 64; ++w) v2 += red[w][tid];
        out[b * NQ + tid] = v2;
    }
}

extern "C" void kernel_launch(void* const* d_in, const int* in_sizes, int n_in,
                              void* d_out, int out_size, void* d_ws, size_t ws_size,
                              hipStream_t stream) {
    const float* inputs  = (const float*)d_in[0];
    const float* weights = (const float*)d_in[1];
    float* out = (float*)d_out;
    const int B = in_sizes[0] / NQ;   // 256
    qsim_kernel<<<dim3(B), dim3(THREADS), 0, stream>>>(inputs, weights, out);
}